// Round 20
// baseline (766.801 us; speedup 1.0000x reference)
//
#include <hip/hip_runtime.h>
#include <stdint.h>

#define D_MODEL 2048
#define S_LEN   2048
#define NTOK    4096
#define QKV_N   3072
#define DFF     8192

typedef float  f32x4   __attribute__((ext_vector_type(4)));
typedef float  f32x16  __attribute__((ext_vector_type(16)));
typedef __bf16 bf16x8  __attribute__((ext_vector_type(8)));
typedef unsigned short u16;
typedef unsigned short u16x8 __attribute__((ext_vector_type(8)));

__device__ __forceinline__ float b2f(u16 u){ union{float f; uint32_t i;} v; v.i = ((uint32_t)u) << 16; return v.f; }
__device__ __forceinline__ u16 f2b(float f){
  union{float f; uint32_t i;} v; v.f = f;
  uint32_t r = v.i + 0x7FFFu + ((v.i >> 16) & 1u);
  return (u16)(r >> 16);
}

__device__ __forceinline__ void gload_lds16(const void* gsrc, void* ldst){
  __builtin_amdgcn_global_load_lds(
      (const __attribute__((address_space(1))) void*)gsrc,
      (__attribute__((address_space(3))) void*)ldst,
      16, 0, 0);
}

// ------- grid-stride weight convert+transpose tail (pair + row-interleave capable) ----
__device__ __forceinline__ void conv_tiles(const float* W, const float* W2, u16* WT,
    int Nfull, int Kt, int Nt, int k0g, int n0g, int rmul, void* ldsbuf)
{
  if (W == nullptr) return;
  float* tf = (float*)ldsbuf;
  const int tt  = threadIdx.x;
  const int nTn = Nt >> 6;
  const int nT  = (Kt >> 6) * nTn;
  const int bid = (blockIdx.z * gridDim.y + blockIdx.y) * gridDim.x + blockIdx.x;
  const int gsz = gridDim.x * gridDim.y * gridDim.z;
  const int c4 = (tt & 15) << 2;
  const int r  = tt >> 4;
  for (int tile = bid; tile < nT; tile += gsz) {
    const int k0 = (tile / nTn) << 6, n0 = (tile % nTn) << 6;
    for (int m = 0; m < 2; ++m) {
      const float* Ws = m ? W2 : W;
      if (m && W2 == nullptr) break;
      __syncthreads();
      if (tt < 256) {
#pragma unroll
        for (int i = 0; i < 4; ++i) {
          int row = r + i * 16;
          float4 v = *reinterpret_cast<const float4*>(&Ws[(size_t)(k0g + k0 + row) * Nfull + n0g + n0 + c4]);
          tf[row * 65 + c4 + 0] = v.x; tf[row * 65 + c4 + 1] = v.y;
          tf[row * 65 + c4 + 2] = v.z; tf[row * 65 + c4 + 3] = v.w;
        }
      }
      __syncthreads();
      if (tt < 256) {
#pragma unroll
        for (int i = 0; i < 4; ++i) {
          int n = r + i * 16;
          ushort4 ov;
          ov.x = f2b(tf[(c4 + 0) * 65 + n]); ov.y = f2b(tf[(c4 + 1) * 65 + n]);
          ov.z = f2b(tf[(c4 + 2) * 65 + n]); ov.w = f2b(tf[(c4 + 3) * 65 + n]);
          *reinterpret_cast<ushort4*>(&WT[(size_t)((n0 + n) * rmul + m) * Kt + k0 + c4]) = ov;
        }
      }
    }
  }
}

// ------- rope cos/sin table --------------------------------------------------------
__global__ void sincos_kernel(float* __restrict__ ct, float* __restrict__ st)
{
  int idx = blockIdx.x * 256 + threadIdx.x;
  if (idx >= S_LEN * 32) return;
  int p = idx >> 5, i = idx & 31;
  double freq = pow(10000.0, -((double)(2*i)) / 64.0);
  double ang  = (double)p * freq;
  ct[idx] = (float)cos(ang);
  st[idx] = (float)sin(ang);
}

// ------- RMSNorm (+ conversion tail) -------------------------------------------------
template<bool BF16IN>
__global__ __launch_bounds__(256) void rmsnorm_kernel(const void* __restrict__ xin, const float* __restrict__ w, u16* __restrict__ out,
                                                      const float* cvW, const float* cvW2, u16* cvWT, int cvNfull, int cvKt, int cvNt, int cvK0g, int cvN0g, int cvRm)
{
  __shared__ float tfbuf[64 * 65];
  const int row = blockIdx.x;
  const int t = threadIdx.x;
  float v[8];
  if (BF16IN) {
    const u16* xr = ((const u16*)xin) + (size_t)row * D_MODEL;
    u16x8 a = *reinterpret_cast<const u16x8*>(&xr[t*8]);
#pragma unroll
    for (int j = 0; j < 8; ++j) v[j] = b2f(a[j]);
  } else {
    const float* xr = ((const float*)xin) + (size_t)row * D_MODEL;
    float4 a = *reinterpret_cast<const float4*>(&xr[t*8]);
    float4 c = *reinterpret_cast<const float4*>(&xr[t*8+4]);
    v[0]=a.x; v[1]=a.y; v[2]=a.z; v[3]=a.w; v[4]=c.x; v[5]=c.y; v[6]=c.z; v[7]=c.w;
  }
  float ss = 0.f;
#pragma unroll
  for (int j = 0; j < 8; ++j) ss += v[j]*v[j];
#pragma unroll
  for (int d = 1; d < 64; d <<= 1) ss += __shfl_xor(ss, d);
  __shared__ float red[4];
  if ((t & 63) == 0) red[t >> 6] = ss;
  __syncthreads();
  ss = red[0] + red[1] + red[2] + red[3];
  const float sc = rsqrtf(ss * (1.0f / (float)D_MODEL) + 1e-5f);
  float4 w0 = *reinterpret_cast<const float4*>(&w[t*8]);
  float4 w1 = *reinterpret_cast<const float4*>(&w[t*8+4]);
  u16x8 o;
  o[0]=f2b(v[0]*sc*w0.x); o[1]=f2b(v[1]*sc*w0.y); o[2]=f2b(v[2]*sc*w0.z); o[3]=f2b(v[3]*sc*w0.w);
  o[4]=f2b(v[4]*sc*w1.x); o[5]=f2b(v[5]*sc*w1.y); o[6]=f2b(v[6]*sc*w1.z); o[7]=f2b(v[7]*sc*w1.w);
  *reinterpret_cast<u16x8*>(&out[(size_t)row * D_MODEL + t*8]) = o;
  conv_tiles(cvW, cvW2, cvWT, cvNfull, cvKt, cvNt, cvK0g, cvN0g, cvRm, tfbuf);
}

// ------- shared GEMM epilogue dispatch ------------------------------------------------
template<int EPI>
__device__ __forceinline__ void epi_store(size_t idx, float v, float* Cf, u16* Cb,
                                          const float* resf, const u16* resb, const u16* other)
{
  if (EPI == 2)      Cb[idx] = f2b(v / (1.0f + __expf(-v)));
  else if (EPI == 3) Cb[idx] = f2b(v * b2f(other[idx]));
  else if (EPI == 4) Cb[idx] = f2b(v);
  else if (EPI == 5) Cf[idx] += v;
  else if (EPI == 6) Cb[idx] = f2b(v + resf[idx]);
  else if (EPI == 7) Cf[idx] = v + b2f(resb[idx]);
  else if (EPI == 9) {
    float pv = __shfl_xor(v, 1);
    float gate = (threadIdx.x & 1) ? pv : v;
    float up   = (threadIdx.x & 1) ? v  : pv;
    if (!(threadIdx.x & 1)) Cb[idx] = f2b(gate / (1.0f + __expf(-gate)) * up);
  }
}

// ------- 256x256 8-phase bf16 MFMA GEMM: A[M][lda] x BT[N][ldb] -----------------------
// Single barrier per phase; compiler schedules fine-grained lgkmcnt before MFMA use.
template<int EPI>
__global__ __launch_bounds__(512, 2) void gemm8p_kernel(
    const u16* __restrict__ A, const u16* __restrict__ BT, const u16* __restrict__ BT2,
    int K, int lda, int ldb, int ldc, int n_off,
    float* Cf, u16* Cb,
    const float* __restrict__ resf, const u16* __restrict__ resb, const u16* other,
    const float* cvW, const float* cvW2, u16* cvWT, int cvNfull, int cvKt, int cvNt, int cvK0g, int cvN0g, int cvRm)
{
  __shared__ u16 lds[65536];
  const int tid = threadIdx.x;
  const int w = tid >> 6, lane = tid & 63;
  const int g = lane >> 4, lr = lane & 15;
  const int wm = w >> 2, wn = w & 3;
  int fid = blockIdx.y * gridDim.x + blockIdx.x;
  const int nwg = gridDim.x * gridDim.y;
  fid = (fid & 7) * (nwg >> 3) + (fid >> 3);      // XCD swizzle (nwg % 8 == 0)
  const int bn = fid / gridDim.y, bm = fid % gridDim.y;   // column-major: bn-stripe/XCD
  const int NT = K >> 6;
  const int NI = NT >> 1;

  const int srow = tid >> 3;
  const int sg   = (tid & 7) ^ (srow & 7);
  const u16* Asrc = A + (size_t)(bm * 256) * lda;
  const u16* Bsrc;
  if (EPI == 9) Bsrc = (bn < 16) ? BT + (size_t)(bn * 256) * ldb
                                 : BT2 + (size_t)(bn * 256 - 4096) * ldb;
  else          Bsrc = BT + (size_t)(bn * 256) * ldb;

  const int agc0 = ((0 + g) ^ (lr & 7)) * 8;
  const int agc1 = ((4 + g) ^ (lr & 7)) * 8;

  f32x4 acc[8][4];
#pragma unroll
  for (int i = 0; i < 8; ++i)
#pragma unroll
    for (int j = 0; j < 4; ++j) acc[i][j] = (f32x4){0.f, 0.f, 0.f, 0.f};
  bf16x8 af[4][2], bf0[2][2], bf1[2][2];

#define STAGE_H(isB, h, b, T) do {                                           \
    int tc = ((T) < NT) ? (T) : (NT - 1);                                    \
    const u16* sb = (isB) ? Bsrc : Asrc;                                     \
    const int  sld = (isB) ? ldb : lda;                                      \
    const u16* s0 = sb + (size_t)((h)*128 + srow) * sld + tc*64 + sg*8;      \
    u16* dst = &lds[(b)*32768 + (isB)*16384 + (h)*8192 + tid*8];             \
    gload_lds16(s0, dst);                                                    \
    gload_lds16(s0 + (size_t)64 * sld, dst + 4096);                          \
  } while (0)

#define LOADA(mih, b) { _Pragma("unroll") for (int q = 0; q < 4; ++q) {      \
    const u16* rp = &lds[(b)*32768 + (wm*128 + (mih)*64 + q*16 + lr) * 64];  \
    af[q][0] = *(const bf16x8*)(rp + agc0);                                  \
    af[q][1] = *(const bf16x8*)(rp + agc1); } }

#define LOADB(dst, nih, b) { _Pragma("unroll") for (int nq = 0; nq < 2; ++nq) { \
    const u16* rp = &lds[(b)*32768 + 16384 + (wn*64 + (nih)*32 + nq*16 + lr) * 64]; \
    dst[nq][0] = *(const bf16x8*)(rp + agc0);                                \
    dst[nq][1] = *(const bf16x8*)(rp + agc1); } }

#define MM(mih, nih, BF) {                                                   \
    __builtin_amdgcn_s_setprio(1);                                           \
    _Pragma("unroll") for (int kk = 0; kk < 2; ++kk)                         \
      _Pragma("unroll") for (int q = 0; q < 4; ++q)                          \
        _Pragma("unroll") for (int nq = 0; nq < 2; ++nq)                     \
          acc[(mih)*4+q][(nih)*2+nq] = __builtin_amdgcn_mfma_f32_16x16x32_bf16( \
              af[q][kk], BF[nq][kk], acc[(mih)*4+q][(nih)*2+nq], 0, 0, 0);   \
    __builtin_amdgcn_s_setprio(0); }

#define PHEND     __builtin_amdgcn_s_barrier();
#define PHEND_VM  asm volatile("s_waitcnt vmcnt(4)" ::: "memory");           \
                  __builtin_amdgcn_s_barrier();

  STAGE_H(0, 0, 0, 0); STAGE_H(0, 1, 0, 0);
  STAGE_H(1, 0, 0, 0); STAGE_H(1, 1, 0, 0);
  STAGE_H(1, 0, 1, 1); STAGE_H(1, 1, 1, 1);
  asm volatile("s_waitcnt vmcnt(4)" ::: "memory");
  __builtin_amdgcn_s_barrier();

  for (int i = 0; i < NI; ++i) {
    const int t0 = 2 * i;
    LOADA(0, 0); LOADB(bf0, 0, 0);
    STAGE_H(0, 0, 1, t0 + 1);
    MM(0, 0, bf0); PHEND;
    LOADB(bf1, 1, 0);
    STAGE_H(0, 1, 1, t0 + 1);
    MM(0, 1, bf1); PHEND;
    LOADA(1, 0);
    STAGE_H(1, 0, 0, t0 + 2);
    MM(1, 1, bf1); PHEND;
    STAGE_H(1, 1, 0, t0 + 2);
    MM(1, 0, bf0); PHEND_VM;
    LOADA(0, 1); LOADB(bf0, 0, 1);
    STAGE_H(0, 0, 0, t0 + 2);
    MM(0, 0, bf0); PHEND;
    LOADB(bf1, 1, 1);
    STAGE_H(0, 1, 0, t0 + 2);
    MM(0, 1, bf1); PHEND;
    LOADA(1, 1);
    STAGE_H(1, 0, 1, t0 + 3);
    MM(1, 1, bf1); PHEND;
    STAGE_H(1, 1, 1, t0 + 3);
    MM(1, 0, bf0); PHEND_VM;
  }
#undef STAGE_H
#undef LOADA
#undef LOADB
#undef MM

#pragma unroll
  for (int mi = 0; mi < 8; ++mi) {
    const int rowOff = (mi >> 2) * 64 + (mi & 3) * 16;
#pragma unroll
    for (int ni = 0; ni < 4; ++ni) {
      const int colOff = (ni >> 1) * 32 + (ni & 1) * 16;
#pragma unroll
      for (int j = 0; j < 4; ++j) {
        int row = bm*256 + wm*128 + rowOff + g*4 + j;
        int col = n_off + bn*256 + wn*64 + colOff + lr;
        size_t idx = (EPI == 9) ? ((size_t)row * ldc + (col >> 1))
                                : ((size_t)row * ldc + col);
        epi_store<EPI>(idx, acc[mi][ni][j], Cf, Cb, resf, resb, other);
      }
    }
  }
  conv_tiles(cvW, cvW2, cvWT, cvNfull, cvKt, cvNt, cvK0g, cvN0g, cvRm, lds);
}

// ------- 128x256 8-phase bf16 MFMA GEMM (two conversion-tail descriptors) -------------
template<int EPI>
__global__ __launch_bounds__(512) void gemm128_kernel(
    const u16* __restrict__ A, const u16* __restrict__ BT,
    int K, int lda, int ldb, int ldc, int n_off,
    float* Cf, u16* Cb,
    const float* __restrict__ resf, const u16* __restrict__ resb, const u16* other,
    const float* c1W, const float* c1W2, u16* c1WT, int c1Nfull, int c1Kt, int c1Nt, int c1K0g, int c1N0g, int c1Rm,
    const float* c2W, const float* c2W2, u16* c2WT, int c2Nfull, int c2Kt, int c2Nt, int c2K0g, int c2N0g, int c2Rm)
{
  __shared__ u16 lds[49152];
  const int tid = threadIdx.x;
  const int w = tid >> 6, lane = tid & 63;
  const int g = lane >> 4, lr = lane & 15;
  const int wm = w >> 2, wn = w & 3;
  int fid = blockIdx.y * gridDim.x + blockIdx.x;
  const int nwg = gridDim.x * gridDim.y;
  fid = (fid & 7) * (nwg >> 3) + (fid >> 3);      // XCD swizzle (nwg % 8 == 0)
  const int bn = fid / gridDim.y, bm = fid % gridDim.y;   // column-major: bn-stripe/XCD
  const int NT = K >> 6;
  const int NI = NT >> 1;

  const int srow = tid >> 3;
  const int sg   = (tid & 7) ^ (srow & 7);
  const u16* Asrc = A  + (size_t)(bm * 128) * lda;
  const u16* Bsrc = BT + (size_t)(bn * 256) * ldb;

  const int agc0 = ((0 + g) ^ (lr & 7)) * 8;
  const int agc1 = ((4 + g) ^ (lr & 7)) * 8;

  f32x4 acc[4][4];
#pragma unroll
  for (int i = 0; i < 4; ++i)
#pragma unroll
    for (int j = 0; j < 4; ++j) acc[i][j] = (f32x4){0.f, 0.f, 0.f, 0.f};
  bf16x8 af[2][2], bf0[2][2], bf1[2][2];

#define STAGE_A(b, T) do {                                                   \
    int tc = ((T) < NT) ? (T) : (NT - 1);                                    \
    const u16* s0 = Asrc + (size_t)srow * lda + tc*64 + sg*8;                \
    u16* dst = &lds[(b)*24576 + tid*8];                                      \
    gload_lds16(s0, dst);                                                    \
    gload_lds16(s0 + (size_t)64 * lda, dst + 4096);                          \
  } while (0)

#define STAGE_BH(h, b, T) do {                                               \
    int tc = ((T) < NT) ? (T) : (NT - 1);                                    \
    const u16* s0 = Bsrc + (size_t)((h)*128 + srow) * ldb + tc*64 + sg*8;    \
    u16* dst = &lds[(b)*24576 + 8192 + (h)*8192 + tid*8];                    \
    gload_lds16(s0, dst);                                                    \
    gload_lds16(s0 + (size_t)64 * ldb, dst + 4096);                         \
  } while (0)

#define LOADA(mih, b) { _Pragma("unroll") for (int q = 0; q < 2; ++q) {      \
    const u16* rp = &lds[(b)*24576 + (wm*64 + (mih)*32 + q*16 + lr) * 64];   \
    af[q][0] = *(const bf16x8*)(rp + agc0);                                  \
    af[q][1] = *(const bf16x8*)(rp + agc1); } }

#define LOADB(dst, nih, b) { _Pragma("unroll") for (int nq = 0; nq < 2; ++nq) { \
    const u16* rp = &lds[(b)*24576 + 8192 + (wn*64 + (nih)*32 + nq*16 + lr) * 64]; \
    dst[nq][0] = *(const bf16x8*)(rp + agc0);                                \
    dst[nq][1] = *(const bf16x8*)(rp + agc1); } }

#define MM(mih, nih, BF) {                                                   \
    __builtin_amdgcn_s_setprio(1);                                           \
    _Pragma("unroll") for (int kk = 0; kk < 2; ++kk)                         \
      _Pragma("unroll") for (int q = 0; q < 2; ++q)                          \
        _Pragma("unroll") for (int nq = 0; nq < 2; ++nq)                     \
          acc[(mih)*2+q][(nih)*2+nq] = __builtin_amdgcn_mfma_f32_16x16x32_bf16( \
              af[q][kk], BF[nq][kk], acc[(mih)*2+q][(nih)*2+nq], 0, 0, 0);   \
    __builtin_amdgcn_s_setprio(0); }

#define PHEND     __builtin_amdgcn_s_barrier();

  STAGE_A(0, 0); STAGE_BH(0, 0, 0); STAGE_BH(1, 0, 0);
  STAGE_BH(0, 1, 1); STAGE_BH(1, 1, 1);
  asm volatile("s_waitcnt vmcnt(4)" ::: "memory");
  __builtin_amdgcn_s_barrier();

  for (int i = 0; i < NI; ++i) {
    const int t0 = 2 * i;
    LOADA(0, 0); LOADB(bf0, 0, 0);
    STAGE_A(1, t0 + 1);
    MM(0, 0, bf0); PHEND;
    LOADB(bf1, 1, 0);
    STAGE_BH(0, 0, t0 + 2);
    MM(0, 1, bf1); PHEND;
    LOADA(1, 0);
    STAGE_BH(1, 0, t0 + 2);
    MM(1, 1, bf1); PHEND;
    STAGE_A(0, t0 + 2);
    MM(1, 0, bf0);
    asm volatile("s_waitcnt vmcnt(6)" ::: "memory");
    __builtin_amdgcn_s_barrier();
    LOADA(0, 1); LOADB(bf0, 0, 1);
    MM(0, 0, bf0); PHEND;
    LOADB(bf1, 1, 1);
    STAGE_BH(0, 1, t0 + 3);
    MM(0, 1, bf1); PHEND;
    LOADA(1, 1);
    STAGE_BH(1, 1, t0 + 3);
    MM(1, 1, bf1); PHEND;
    MM(1, 0, bf0);
    asm volatile("s_waitcnt vmcnt(4)" ::: "memory");
    __builtin_amdgcn_s_barrier();
  }
#undef STAGE_A
#undef STAGE_BH
#undef LOADA
#undef LOADB
#undef MM
#undef PHEND

#pragma unroll
  for (int mi = 0; mi < 4; ++mi) {
    const int rowOff = (mi >> 1) * 32 + (mi & 1) * 16;
#pragma unroll
    for (int ni = 0; ni < 4; ++ni) {
      const int colOff = (ni >> 1) * 32 + (ni & 1) * 16;
#pragma unroll
      for (int j = 0; j < 4; ++j) {
        int row = bm*128 + wm*64 + rowOff + g*4 + j;
        int col = n_off + bn*256 + wn*64 + colOff + lr;
        epi_store<EPI>((size_t)row * ldc + col, acc[mi][ni][j], Cf, Cb, resf, resb, other);
      }
    }
  }
  conv_tiles(c1W, c1W2, c1WT, c1Nfull, c1Kt, c1Nt, c1K0g, c1N0g, c1Rm, lds);
  conv_tiles(c2W, c2W2, c2WT, c2Nfull, c2Kt, c2Nt, c2K0g, c2N0g, c2Rm, lds);
}

// ------- RoPE + relayout for K, V only ------------------------------------------------
__global__ __launch_bounds__(256) void rope_kernel(
    const u16* __restrict__ qkv, const float* __restrict__ ct, const float* __restrict__ st,
    u16* __restrict__ Kt, u16* __restrict__ VT)
{
  const int tok = blockIdx.x;
  const int b = tok >> 11, s = tok & (S_LEN - 1);
  const int w = threadIdx.x >> 6, lane = threadIdx.x & 63;
  const size_t base = (size_t)tok * QKV_N;
  for (int slot = w; slot < 16; slot += 4) {
    int col = (slot < 8) ? 2048 + slot * 64 : 2560 + (slot - 8) * 64;
    float v = b2f(qkv[base + col + lane]);
    if (slot < 8) {
      int i = lane & 31;
      float c = ct[s * 32 + i], sn = st[s * 32 + i];
      float p = b2f(qkv[base + col + (lane ^ 32)]);
      v = (lane < 32) ? (v * c - p * sn) : (v * c + p * sn);
    }
    u16 ob = f2b(v);
    if (slot < 8) Kt[((size_t)(b * 8 + slot)     * S_LEN + s) * 64 + lane] = ob;
    else          VT[((size_t)(b * 8 + slot - 8) * 64 + lane) * S_LEN + s] = ob;
  }
}

// ------- causal GQA flash attention: fixed-m softmax (shift-invariant, no running max)
// paired q-tiles + XCD bh-partition + KVBLK=64. m == 16 in exp2 domain.
#define ASCALE 0.1803368801111204f   /* 0.125 * log2(e) */
#define MFIX   16.0f
__global__ __launch_bounds__(256, 2) void attn_kernel(
    const u16* __restrict__ qkv, const u16* __restrict__ Kt,
    const u16* __restrict__ VT, u16* __restrict__ ctx,
    const float* __restrict__ ct, const float* __restrict__ st,
    const float* cvW, const float* cvW2, u16* cvWT, int cvNfull, int cvKt, int cvNt, int cvK0g, int cvN0g, int cvRm)
{
  __shared__ float tfbuf[64 * 65];
  const int fid = blockIdx.y * gridDim.x + blockIdx.x;   // 0..511
  const int idx = fid >> 3;                              // 0..63
  const int bh  = (fid & 7) * 8 + (idx & 7);             // XCD-local kv locality
  const int y   = idx >> 3;                              // 0..7
  const int wid = threadIdx.x >> 6;
  const int lane = threadIdx.x & 63;
  const int b = bh >> 5, h = bh & 31;
  const int kvh = (b << 3) + (h >> 2);
  const int jj = y * 4 + wid;                            // 0..31
  const int cq = lane & 31;
  const int hi = lane >> 5;

  const u16* Kp = Kt + (size_t)kvh * S_LEN * 64 + cq * 64 + hi * 8;
  const u16* Vbase = VT + (size_t)kvh * 64 * S_LEN + hi * 8;
  const u16* Vp[4];
#pragma unroll
  for (int v = 0; v < 4; ++v)
    Vp[v] = Vbase + (size_t)((v & 1) * 32 + cq) * S_LEN + (v >> 1) * 16;

  __shared__ float xch[4][32];

#define ATT_LOADK(KF, T) { _Pragma("unroll") for (int q_ = 0; q_ < 4; ++q_) \
    KF[q_] = *(const bf16x8*)(Kp + (T) * 2048 + q_ * 16); }
#define ATT_LOADV(VF, T) { _Pragma("unroll") for (int v_ = 0; v_ < 4; ++v_) \
    VF[v_] = *(const bf16x8*)(Vp[v_] + (T) * 32); }

#define ATT_QK(S, KF) do {                                                   \
    S = (f32x16){};                                                          \
    S = __builtin_amdgcn_mfma_f32_32x32x16_bf16(KF[0], qf[0], S, 0, 0, 0);   \
    S = __builtin_amdgcn_mfma_f32_32x32x16_bf16(KF[1], qf[1], S, 0, 0, 0);   \
    S = __builtin_amdgcn_mfma_f32_32x32x16_bf16(KF[2], qf[2], S, 0, 0, 0);   \
    S = __builtin_amdgcn_mfma_f32_32x32x16_bf16(KF[3], qf[3], S, 0, 0, 0);   \
  } while (0)

#define ATT_PACK(P, PA0, PA1) do {                                           \
    uint32_t wds[8], pw[8];                                                  \
    _Pragma("unroll") for (int j = 0; j < 8; ++j) {                          \
      uint32_t wv;                                                           \
      asm("v_cvt_pk_bf16_f32 %0, %1, %2" : "=v"(wv) : "v"((P)[2*j]), "v"((P)[2*j+1])); \
      wds[j] = wv;                                                           \
    }                                                                        \
    _Pragma("unroll") for (int j = 0; j < 8; ++j) pw[j] = __shfl_xor(wds[j], 32); \
    PA0.u[0] = hi ? pw[2]  : wds[0];                                         \
    PA0.u[1] = hi ? pw[3]  : wds[1];                                         \
    PA0.u[2] = hi ? wds[2] : pw[0];                                          \
    PA0.u[3] = hi ? wds[3] : pw[1];                                          \
    PA1.u[0] = hi ? pw[6]  : wds[4];                                         \
    PA1.u[1] = hi ? pw[7]  : wds[5];                                         \
    PA1.u[2] = hi ? wds[6] : pw[4];                                          \
    PA1.u[3] = hi ? wds[7] : pw[5];                                          \
  } while (0)

// single-tile finish (tail; always the last tile -> mask applied); fixed m
#define ATT_FIN1(S, VF) do {                                                 \
    float p[16];                                                             \
    _Pragma("unroll") for (int r = 0; r < 16; ++r) p[r] = S[r];              \
    _Pragma("unroll") for (int r = 0; r < 16; ++r) {                         \
      int kk = (r & 3) + 8 * (r >> 2) + 4 * hi;                              \
      if (kk > cq) p[r] = -1e30f;                                            \
    }                                                                        \
    float ts_ = 0.f;                                                         \
    _Pragma("unroll") for (int r = 0; r < 16; ++r) { p[r] = exp2f(p[r] - MFIX); ts_ += p[r]; } \
    l += ts_;                                                                \
    union { uint32_t u[4]; bf16x8 v; } pa0, pa1;                             \
    ATT_PACK(p, pa0, pa1);                                                   \
    o0 = __builtin_amdgcn_mfma_f32_32x32x16_bf16(pa0.v, VF[0], o0, 0, 0, 0); \
    o0 = __builtin_amdgcn_mfma_f32_32x32x16_bf16(pa1.v, VF[2], o0, 0, 0, 0); \
    o1 = __builtin_amdgcn_mfma_f32_32x32x16_bf16(pa0.v, VF[1], o1, 0, 0, 0); \
    o1 = __builtin_amdgcn_mfma_f32_32x32x16_bf16(pa1.v, VF[3], o1, 0, 0, 0); \
  } while (0)

// pair finish: tiles A,B, fixed m, no cross-tile serial state except l and o (accum)
#define ATT_FIN2(SA, SB, VFA, VFB, MASKB) do {                               \
    float p[32];                                                             \
    _Pragma("unroll") for (int r = 0; r < 16; ++r) { p[r] = SA[r]; p[16+r] = SB[r]; } \
    if (MASKB) {                                                             \
      _Pragma("unroll") for (int r = 0; r < 16; ++r) {                       \
        int kk = (r & 3) + 8 * (r >> 2) + 4 * hi;                            \
        if (kk > cq) p[16+r] = -1e30f;                                       \
      }                                                                      \
    }                                                                        \
    _Pragma("unroll") for (int r = 0; r < 32; ++r) p[r] = exp2f(p[r] - MFIX); \
    {                                                                        \
      float s1_ = 0.f, s2_ = 0.f;                                            \
      _Pragma("unroll") for (int r = 0; r < 16; ++r) { s1_ += p[r]; s2_ += p[16+r]; } \
      l += s1_ + s2_;                                                        \
    }                                                                        \
    union { uint32_t u[4]; bf16x8 v; } pa0, pa1, pb0, pb1;                   \
    ATT_PACK(p, pa0, pa1);                                                   \
    ATT_PACK((p + 16), pb0, pb1);                                            \
    o0 = __builtin_amdgcn_mfma_f32_32x32x16_bf16(pa0.v, VFA[0], o0, 0, 0, 0); \
    o0 = __builtin_amdgcn_mfma_f32_32x32x16_bf16(pa1.v, VFA[2], o0, 0, 0, 0); \
    o1 = __builtin_amdgcn_mfma_f32_32x32x16_bf16(pa0.v, VFA[1], o1, 0, 0, 0); \
    o1 = __builtin_amdgcn_mfma_f32_32x32x16_bf16(pa1.v, VFA[3], o1, 0, 0, 0); \
    o0 = __builtin_amdgcn_mfma_f32_32x32x16_bf16(pb0.v, VFB[0], o0, 0, 0, 0); \
    o0 = __builtin_amdgcn_mfma_f32_32x32x16_bf16(pb1.v, VFB[2], o0, 0, 0, 0); \
    o1 = __builtin_amdgcn_mfma_f32_32x32x16_bf16(pb0.v, VFB[1], o1, 0, 0, 0); \
    o1 = __builtin_amdgcn_mfma_f32_32x32x16_bf16(pb1.v, VFB[3], o1, 0, 0, 0); \
  } while (0)

#pragma unroll 1
  for (int task = 0; task < 2; ++task) {
    const int qt = task ? (63 - jj) : jj;
    const int q0 = qt << 5;
    const int nt = qt + 1;

    bf16x8 qf[4];
    {
      const u16* Qr = qkv + (size_t)(b * S_LEN + q0 + cq) * QKV_N + h * 64 + hi * 8;
      u16 qr[4][8];
#pragma unroll
      for (int t = 0; t < 4; ++t)
        *reinterpret_cast<u16x8*>(qr[t]) = *reinterpret_cast<const u16x8*>(Qr + t * 16);
      const float* cb = ct + (size_t)(q0 + cq) * 32 + hi * 8;
      const float* sb = st + (size_t)(q0 + cq) * 32 + hi * 8;
      union { u16 u[8]; bf16x8 v; } qo[4];
#pragma unroll
      for (int t = 0; t < 2; ++t) {
        float4 c0 = *reinterpret_cast<const float4*>(cb + 16 * t);
        float4 c1 = *reinterpret_cast<const float4*>(cb + 16 * t + 4);
        float4 s0 = *reinterpret_cast<const float4*>(sb + 16 * t);
        float4 s1 = *reinterpret_cast<const float4*>(sb + 16 * t + 4);
        float cc[8] = {c0.x,c0.y,c0.z,c0.w, c1.x,c1.y,c1.z,c1.w};
        float ssn[8] = {s0.x,s0.y,s0.z,s0.w, s1.x,s1.y,s1.z,s1.w};
#pragma unroll
        for (int i = 0; i < 8; ++i) {
          float lo = b2f(qr[t][i]), hif = b2f(qr[t + 2][i]);
          qo[t].u[i]     = f2b((lo * cc[i] - hif * ssn[i]) * ASCALE);
          qo[t + 2].u[i] = f2b((hif * cc[i] + lo * ssn[i]) * ASCALE);
        }
      }
#pragma unroll
      for (int t = 0; t < 4; ++t) qf[t] = qo[t].v;
    }

    f32x16 o0 = {}, o1 = {};
    float l = 0.f;

    const int npair = nt >> 1;
    bf16x8 kfA[4], kfB[4], vfA[4], vfB[4];

#pragma unroll 1
    for (int i = 0; i < npair; ++i) {
      const int Ta = 2 * i, Tb = 2 * i + 1;
      ATT_LOADK(kfA, Ta); ATT_LOADK(kfB, Tb);
      ATT_LOADV(vfA, Ta); ATT_LOADV(vfB, Tb);
      f32x16 sA, sB;
      ATT_QK(sA, kfA); ATT_QK(sB, kfB);
      ATT_FIN2(sA, sB, vfA, vfB, (Tb == nt - 1));
    }
    if (nt & 1) {
      const int T = nt - 1;
      ATT_LOADK(kfA, T); ATT_LOADV(vfA, T);
      f32x16 sA;
      ATT_QK(sA, kfA);
      ATT_FIN1(sA, vfA);
    }

    l += __shfl_xor(l, 32);
    float linv = 1.0f / l;
    if (hi == 0) xch[wid][cq] = linv;
    asm volatile("s_waitcnt lgkmcnt(0)" ::: "memory");
    __builtin_amdgcn_sched_barrier(0);
    float4 n0 = *reinterpret_cast<const float4*>(&xch[wid][4 * hi + 0]);
    float4 n1 = *reinterpret_cast<const float4*>(&xch[wid][4 * hi + 8]);
    float4 n2 = *reinterpret_cast<const float4*>(&xch[wid][4 * hi + 16]);
    float4 n3 = *reinterpret_cast<const float4*>(&xch[wid][4 * hi + 24]);
    float na[16] = {n0.x,n0.y,n0.z,n0.w, n1.x,n1.y,n1.z,n1.w,
                    n2.x,n2.y,n2.z,n2.w, n3.x,n3.y,n3.z,n3.w};
#pragma unroll
    for (int r = 0; r < 16; ++r) {
      int row = (r & 3) + 8 * (r >> 2) + 4 * hi;
      size_t base = (size_t)(b * S_LEN + q0 + row) * D_MODEL + h * 64;
      ctx[base + cq]      = f2b(o0[r] * na[r]);
      ctx[base + 32 + cq] = f2b(o1[r] * na[r]);
    }
  }
#undef ATT_LOADK
#undef ATT_LOADV
#undef ATT_QK
#undef ATT_PACK
#undef ATT_FIN1
#undef ATT_FIN2

  conv_tiles(cvW, cvW2, cvWT, cvNfull, cvKt, cvNt, cvK0g, cvN0g, cvRm, tfbuf);
}

// ---------------------------------- host ---------------------------------------------
#define NOCV nullptr, nullptr, nullptr, 0, 0, 0, 0, 0, 1
extern "C" void kernel_launch(void* const* d_in, const int* in_sizes, int n_in,
                              void* d_out, int out_size, void* d_ws, size_t ws_size,
                              hipStream_t stream)
{
  const float* x     = (const float*)d_in[0];
  const float* wn1   = (const float*)d_in[1];
  const float* wqkv  = (const float*)d_in[2];
  const float* wout  = (const float*)d_in[3];
  const float* wn2   = (const float*)d_in[4];
  const float* wgate = (const float*)d_in[5];
  const float* wup   = (const float*)d_in[6];
  const float* wdown = (const float*)d_in[7];
  float* out = (float*)d_out;
  char* ws = (char*)d_ws;

  // arena: 117,964,800 bytes, 16.8MB units
  float* cosT = (float*)(ws + 0);
  float* sinT = (float*)(ws + 262144);
  u16*   U1   = (u16*)  (ws + 524288);
  u16*   U2   = (u16*)  (ws + 17301504);
  u16*   x1b  = (u16*)  (ws + 34078720);
  char*  S    = ws + 50855936;
  u16*   hB   = (u16*)(S + 0);
  u16*   qkvB = (u16*)(S + 16777216);
  u16*   kB   = (u16*)(S + 41943040);
  u16*   vtB  = (u16*)(S + 46137344);
  u16*   ctxB = (u16*)(S + 0);
  u16*   h2B  = (u16*)(S + 0);
  u16*   slab = (u16*)(S + 16777216);
  u16*   U7   = (u16*)(S + 50331648);

  sincos_kernel<<<dim3(256), 256, 0, stream>>>(cosT, sinT);
  // h = rmsnorm(x); tail: wqkv -> U1
  rmsnorm_kernel<false><<<dim3(NTOK), 256, 0, stream>>>(x, wn1, hB,
      wqkv, nullptr, U1, 3072, 2048, 3072, 0, 0, 1);

  // qkv = h @ w_qkv; tail: wout -> U7
  gemm128_kernel<4><<<dim3(12, 32), 512, 0, stream>>>(hB, U1, 2048, 2048, 2048, 3072, 0,
      nullptr, qkvB, nullptr, nullptr, nullptr,
      wout, nullptr, U7, 2048, 2048, 2048, 0, 0, 1, NOCV);
  rope_kernel<<<dim3(NTOK), 256, 0, stream>>>(qkvB, cosT, sinT, kB, vtB);
  // attn (fixed-m softmax); tail: interleaved gate/up c0-lo -> U1
  attn_kernel<<<dim3(64, 8), 256, 0, stream>>>(qkvB, kB, vtB, ctxB, cosT, sinT,
      wgate, wup, U1, 8192, 2048, 2048, 0, 0, 2);

  // x1 = x + ctx @ w_out; tail: gate/up c0-hi -> U2
  gemm128_kernel<6><<<dim3(8, 32), 512, 0, stream>>>(ctxB, U7, 2048, 2048, 2048, 2048, 0,
      nullptr, x1b, x, nullptr, nullptr,
      wgate, wup, U2, 8192, 2048, 2048, 0, 2048, 2, NOCV);

  // h2 = rmsnorm(x1); tail: wdown rows 0..4095 -> U7
  rmsnorm_kernel<true><<<dim3(NTOK), 256, 0, stream>>>(x1b, wn2, h2B,
      wdown, nullptr, U7, 2048, 4096, 2048, 0, 0, 1);

  // slab = silu(h2 @ gate_c0) * (h2 @ up_c0)
  gemm8p_kernel<9><<<dim3(32, 16), 512, 0, stream>>>(h2B, U1, U2, 2048, 2048, 2048, 4096, 0,
      nullptr, slab, nullptr, nullptr, nullptr, NOCV);
  // out = x1 + slab @ down_c0; tails: gate/up c1-lo -> U1, c1-hi -> U2
  gemm128_kernel<7><<<dim3(8, 32), 512, 0, stream>>>(slab, U7, 4096, 4096, 4096, 2048, 0,
      out, nullptr, nullptr, x1b, nullptr,
      wgate, wup, U1, 8192, 2048, 2048, 0, 4096, 2,
      wgate, wup, U2, 8192, 2048, 2048, 0, 6144, 2);
  // slab = silu(h2 @ gate_c1) * (h2 @ up_c1); tail: wdown rows 4096..8191 -> U7
  gemm8p_kernel<9><<<dim3(32, 16), 512, 0, stream>>>(h2B, U1, U2, 2048, 2048, 2048, 4096, 0,
      nullptr, slab, nullptr, nullptr, nullptr,
      wdown, nullptr, U7, 2048, 4096, 2048, 4096, 0, 1);
  // out += slab @ down_c1
  gemm128_kernel<5><<<dim3(8, 32), 512, 0, stream>>>(slab, U7, 4096, 4096, 4096, 2048, 0,
      out, nullptr, nullptr, nullptr, nullptr, NOCV, NOCV);
}

// Round 21
// 748.611 us; speedup vs baseline: 1.0243x; 1.0243x over previous
//
#include <hip/hip_runtime.h>
#include <stdint.h>

#define D_MODEL 2048
#define S_LEN   2048
#define NTOK    4096
#define QKV_N   3072
#define DFF     8192

typedef float  f32x4   __attribute__((ext_vector_type(4)));
typedef float  f32x16  __attribute__((ext_vector_type(16)));
typedef __bf16 bf16x8  __attribute__((ext_vector_type(8)));
typedef unsigned short u16;
typedef unsigned short u16x8 __attribute__((ext_vector_type(8)));

__device__ __forceinline__ float b2f(u16 u){ union{float f; uint32_t i;} v; v.i = ((uint32_t)u) << 16; return v.f; }
__device__ __forceinline__ u16 f2b(float f){
  union{float f; uint32_t i;} v; v.f = f;
  uint32_t r = v.i + 0x7FFFu + ((v.i >> 16) & 1u);
  return (u16)(r >> 16);
}

__device__ __forceinline__ void gload_lds16(const void* gsrc, void* ldst){
  __builtin_amdgcn_global_load_lds(
      (const __attribute__((address_space(1))) void*)gsrc,
      (__attribute__((address_space(3))) void*)ldst,
      16, 0, 0);
}

// ------- grid-stride weight convert+transpose tail (pair + row-interleave capable) ----
__device__ __forceinline__ void conv_tiles(const float* W, const float* W2, u16* WT,
    int Nfull, int Kt, int Nt, int k0g, int n0g, int rmul, void* ldsbuf)
{
  if (W == nullptr) return;
  float* tf = (float*)ldsbuf;
  const int tt  = threadIdx.x;
  const int nTn = Nt >> 6;
  const int nT  = (Kt >> 6) * nTn;
  const int bid = (blockIdx.z * gridDim.y + blockIdx.y) * gridDim.x + blockIdx.x;
  const int gsz = gridDim.x * gridDim.y * gridDim.z;
  const int c4 = (tt & 15) << 2;
  const int r  = tt >> 4;
  for (int tile = bid; tile < nT; tile += gsz) {
    const int k0 = (tile / nTn) << 6, n0 = (tile % nTn) << 6;
    for (int m = 0; m < 2; ++m) {
      const float* Ws = m ? W2 : W;
      if (m && W2 == nullptr) break;
      __syncthreads();
      if (tt < 256) {
#pragma unroll
        for (int i = 0; i < 4; ++i) {
          int row = r + i * 16;
          float4 v = *reinterpret_cast<const float4*>(&Ws[(size_t)(k0g + k0 + row) * Nfull + n0g + n0 + c4]);
          tf[row * 65 + c4 + 0] = v.x; tf[row * 65 + c4 + 1] = v.y;
          tf[row * 65 + c4 + 2] = v.z; tf[row * 65 + c4 + 3] = v.w;
        }
      }
      __syncthreads();
      if (tt < 256) {
#pragma unroll
        for (int i = 0; i < 4; ++i) {
          int n = r + i * 16;
          ushort4 ov;
          ov.x = f2b(tf[(c4 + 0) * 65 + n]); ov.y = f2b(tf[(c4 + 1) * 65 + n]);
          ov.z = f2b(tf[(c4 + 2) * 65 + n]); ov.w = f2b(tf[(c4 + 3) * 65 + n]);
          *reinterpret_cast<ushort4*>(&WT[(size_t)((n0 + n) * rmul + m) * Kt + k0 + c4]) = ov;
        }
      }
    }
  }
}

// ------- rope cos/sin table --------------------------------------------------------
__global__ void sincos_kernel(float* __restrict__ ct, float* __restrict__ st)
{
  int idx = blockIdx.x * 256 + threadIdx.x;
  if (idx >= S_LEN * 32) return;
  int p = idx >> 5, i = idx & 31;
  double freq = pow(10000.0, -((double)(2*i)) / 64.0);
  double ang  = (double)p * freq;
  ct[idx] = (float)cos(ang);
  st[idx] = (float)sin(ang);
}

// ------- RMSNorm (+ conversion tail) -------------------------------------------------
template<bool BF16IN>
__global__ __launch_bounds__(256) void rmsnorm_kernel(const void* __restrict__ xin, const float* __restrict__ w, u16* __restrict__ out,
                                                      const float* cvW, const float* cvW2, u16* cvWT, int cvNfull, int cvKt, int cvNt, int cvK0g, int cvN0g, int cvRm)
{
  __shared__ float tfbuf[64 * 65];
  const int row = blockIdx.x;
  const int t = threadIdx.x;
  float v[8];
  if (BF16IN) {
    const u16* xr = ((const u16*)xin) + (size_t)row * D_MODEL;
    u16x8 a = *reinterpret_cast<const u16x8*>(&xr[t*8]);
#pragma unroll
    for (int j = 0; j < 8; ++j) v[j] = b2f(a[j]);
  } else {
    const float* xr = ((const float*)xin) + (size_t)row * D_MODEL;
    float4 a = *reinterpret_cast<const float4*>(&xr[t*8]);
    float4 c = *reinterpret_cast<const float4*>(&xr[t*8+4]);
    v[0]=a.x; v[1]=a.y; v[2]=a.z; v[3]=a.w; v[4]=c.x; v[5]=c.y; v[6]=c.z; v[7]=c.w;
  }
  float ss = 0.f;
#pragma unroll
  for (int j = 0; j < 8; ++j) ss += v[j]*v[j];
#pragma unroll
  for (int d = 1; d < 64; d <<= 1) ss += __shfl_xor(ss, d);
  __shared__ float red[4];
  if ((t & 63) == 0) red[t >> 6] = ss;
  __syncthreads();
  ss = red[0] + red[1] + red[2] + red[3];
  const float sc = rsqrtf(ss * (1.0f / (float)D_MODEL) + 1e-5f);
  float4 w0 = *reinterpret_cast<const float4*>(&w[t*8]);
  float4 w1 = *reinterpret_cast<const float4*>(&w[t*8+4]);
  u16x8 o;
  o[0]=f2b(v[0]*sc*w0.x); o[1]=f2b(v[1]*sc*w0.y); o[2]=f2b(v[2]*sc*w0.z); o[3]=f2b(v[3]*sc*w0.w);
  o[4]=f2b(v[4]*sc*w1.x); o[5]=f2b(v[5]*sc*w1.y); o[6]=f2b(v[6]*sc*w1.z); o[7]=f2b(v[7]*sc*w1.w);
  *reinterpret_cast<u16x8*>(&out[(size_t)row * D_MODEL + t*8]) = o;
  conv_tiles(cvW, cvW2, cvWT, cvNfull, cvKt, cvNt, cvK0g, cvN0g, cvRm, tfbuf);
}

// ------- shared GEMM epilogue dispatch ------------------------------------------------
template<int EPI>
__device__ __forceinline__ void epi_store(size_t idx, float v, float* Cf, u16* Cb,
                                          const float* resf, const u16* resb, const u16* other)
{
  if (EPI == 2)      Cb[idx] = f2b(v / (1.0f + __expf(-v)));
  else if (EPI == 3) Cb[idx] = f2b(v * b2f(other[idx]));
  else if (EPI == 4) Cb[idx] = f2b(v);
  else if (EPI == 5) Cf[idx] += v;
  else if (EPI == 6) Cb[idx] = f2b(v + resf[idx]);
  else if (EPI == 7) Cf[idx] = v + b2f(resb[idx]);
  else if (EPI == 9) {
    float pv = __shfl_xor(v, 1);
    float gate = (threadIdx.x & 1) ? pv : v;
    float up   = (threadIdx.x & 1) ? v  : pv;
    if (!(threadIdx.x & 1)) Cb[idx] = f2b(gate / (1.0f + __expf(-gate)) * up);
  }
}

// ------- 256x256 8-phase bf16 MFMA GEMM: A[M][lda] x BT[N][ldb] -----------------------
template<int EPI>
__global__ __launch_bounds__(512, 2) void gemm8p_kernel(
    const u16* __restrict__ A, const u16* __restrict__ BT, const u16* __restrict__ BT2,
    int K, int lda, int ldb, int ldc, int n_off,
    float* Cf, u16* Cb,
    const float* __restrict__ resf, const u16* __restrict__ resb, const u16* other,
    const float* cvW, const float* cvW2, u16* cvWT, int cvNfull, int cvKt, int cvNt, int cvK0g, int cvN0g, int cvRm)
{
  __shared__ u16 lds[65536];
  const int tid = threadIdx.x;
  const int w = tid >> 6, lane = tid & 63;
  const int g = lane >> 4, lr = lane & 15;
  const int wm = w >> 2, wn = w & 3;
  int fid = blockIdx.y * gridDim.x + blockIdx.x;
  const int nwg = gridDim.x * gridDim.y;
  fid = (fid & 7) * (nwg >> 3) + (fid >> 3);      // XCD swizzle (nwg % 8 == 0)
  const int bn = fid / gridDim.y, bm = fid % gridDim.y;   // column-major: bn-stripe/XCD
  const int NT = K >> 6;
  const int NI = NT >> 1;

  const int srow = tid >> 3;
  const int sg   = (tid & 7) ^ (srow & 7);
  const u16* Asrc = A + (size_t)(bm * 256) * lda;
  const u16* Bsrc;
  if (EPI == 9) Bsrc = (bn < 16) ? BT + (size_t)(bn * 256) * ldb
                                 : BT2 + (size_t)(bn * 256 - 4096) * ldb;
  else          Bsrc = BT + (size_t)(bn * 256) * ldb;

  const int agc0 = ((0 + g) ^ (lr & 7)) * 8;
  const int agc1 = ((4 + g) ^ (lr & 7)) * 8;

  f32x4 acc[8][4];
#pragma unroll
  for (int i = 0; i < 8; ++i)
#pragma unroll
    for (int j = 0; j < 4; ++j) acc[i][j] = (f32x4){0.f, 0.f, 0.f, 0.f};
  bf16x8 af[4][2], bf0[2][2], bf1[2][2];

#define STAGE_H(isB, h, b, T) do {                                           \
    int tc = ((T) < NT) ? (T) : (NT - 1);                                    \
    const u16* sb = (isB) ? Bsrc : Asrc;                                     \
    const int  sld = (isB) ? ldb : lda;                                      \
    const u16* s0 = sb + (size_t)((h)*128 + srow) * sld + tc*64 + sg*8;      \
    u16* dst = &lds[(b)*32768 + (isB)*16384 + (h)*8192 + tid*8];             \
    gload_lds16(s0, dst);                                                    \
    gload_lds16(s0 + (size_t)64 * sld, dst + 4096);                          \
  } while (0)

#define LOADA(mih, b) { _Pragma("unroll") for (int q = 0; q < 4; ++q) {      \
    const u16* rp = &lds[(b)*32768 + (wm*128 + (mih)*64 + q*16 + lr) * 64];  \
    af[q][0] = *(const bf16x8*)(rp + agc0);                                  \
    af[q][1] = *(const bf16x8*)(rp + agc1); } }

#define LOADB(dst, nih, b) { _Pragma("unroll") for (int nq = 0; nq < 2; ++nq) { \
    const u16* rp = &lds[(b)*32768 + 16384 + (wn*64 + (nih)*32 + nq*16 + lr) * 64]; \
    dst[nq][0] = *(const bf16x8*)(rp + agc0);                                \
    dst[nq][1] = *(const bf16x8*)(rp + agc1); } }

#define MM(mih, nih, BF) {                                                   \
    __builtin_amdgcn_s_setprio(1);                                           \
    _Pragma("unroll") for (int kk = 0; kk < 2; ++kk)                         \
      _Pragma("unroll") for (int q = 0; q < 4; ++q)                          \
        _Pragma("unroll") for (int nq = 0; nq < 2; ++nq)                     \
          acc[(mih)*4+q][(nih)*2+nq] = __builtin_amdgcn_mfma_f32_16x16x32_bf16( \
              af[q][kk], BF[nq][kk], acc[(mih)*4+q][(nih)*2+nq], 0, 0, 0);   \
    __builtin_amdgcn_s_setprio(0); }

#define PHEND     __builtin_amdgcn_s_barrier();
#define PHEND_VM  asm volatile("s_waitcnt vmcnt(4)" ::: "memory");           \
                  __builtin_amdgcn_s_barrier();

  STAGE_H(0, 0, 0, 0); STAGE_H(0, 1, 0, 0);
  STAGE_H(1, 0, 0, 0); STAGE_H(1, 1, 0, 0);
  STAGE_H(1, 0, 1, 1); STAGE_H(1, 1, 1, 1);
  asm volatile("s_waitcnt vmcnt(4)" ::: "memory");
  __builtin_amdgcn_s_barrier();

  for (int i = 0; i < NI; ++i) {
    const int t0 = 2 * i;
    LOADA(0, 0); LOADB(bf0, 0, 0);
    STAGE_H(0, 0, 1, t0 + 1);
    MM(0, 0, bf0); PHEND;
    LOADB(bf1, 1, 0);
    STAGE_H(0, 1, 1, t0 + 1);
    MM(0, 1, bf1); PHEND;
    LOADA(1, 0);
    STAGE_H(1, 0, 0, t0 + 2);
    MM(1, 1, bf1); PHEND;
    STAGE_H(1, 1, 0, t0 + 2);
    MM(1, 0, bf0); PHEND_VM;
    LOADA(0, 1); LOADB(bf0, 0, 1);
    STAGE_H(0, 0, 0, t0 + 2);
    MM(0, 0, bf0); PHEND;
    LOADB(bf1, 1, 1);
    STAGE_H(0, 1, 0, t0 + 2);
    MM(0, 1, bf1); PHEND;
    LOADA(1, 1);
    STAGE_H(1, 0, 1, t0 + 3);
    MM(1, 1, bf1); PHEND;
    STAGE_H(1, 1, 1, t0 + 3);
    MM(1, 0, bf0); PHEND_VM;
  }
#undef STAGE_H
#undef LOADA
#undef LOADB
#undef MM

#pragma unroll
  for (int mi = 0; mi < 8; ++mi) {
    const int rowOff = (mi >> 2) * 64 + (mi & 3) * 16;
#pragma unroll
    for (int ni = 0; ni < 4; ++ni) {
      const int colOff = (ni >> 1) * 32 + (ni & 1) * 16;
#pragma unroll
      for (int j = 0; j < 4; ++j) {
        int row = bm*256 + wm*128 + rowOff + g*4 + j;
        int col = n_off + bn*256 + wn*64 + colOff + lr;
        size_t idx = (EPI == 9) ? ((size_t)row * ldc + (col >> 1))
                                : ((size_t)row * ldc + col);
        epi_store<EPI>(idx, acc[mi][ni][j], Cf, Cb, resf, resb, other);
      }
    }
  }
  conv_tiles(cvW, cvW2, cvWT, cvNfull, cvKt, cvNt, cvK0g, cvN0g, cvRm, lds);
}

// ------- 128x256 8-phase bf16 MFMA GEMM (two conversion-tail descriptors) -------------
template<int EPI>
__global__ __launch_bounds__(512) void gemm128_kernel(
    const u16* __restrict__ A, const u16* __restrict__ BT,
    int K, int lda, int ldb, int ldc, int n_off,
    float* Cf, u16* Cb,
    const float* __restrict__ resf, const u16* __restrict__ resb, const u16* other,
    const float* c1W, const float* c1W2, u16* c1WT, int c1Nfull, int c1Kt, int c1Nt, int c1K0g, int c1N0g, int c1Rm,
    const float* c2W, const float* c2W2, u16* c2WT, int c2Nfull, int c2Kt, int c2Nt, int c2K0g, int c2N0g, int c2Rm)
{
  __shared__ u16 lds[49152];
  const int tid = threadIdx.x;
  const int w = tid >> 6, lane = tid & 63;
  const int g = lane >> 4, lr = lane & 15;
  const int wm = w >> 2, wn = w & 3;
  int fid = blockIdx.y * gridDim.x + blockIdx.x;
  const int nwg = gridDim.x * gridDim.y;
  fid = (fid & 7) * (nwg >> 3) + (fid >> 3);      // XCD swizzle (nwg % 8 == 0)
  const int bn = fid / gridDim.y, bm = fid % gridDim.y;   // column-major: bn-stripe/XCD
  const int NT = K >> 6;
  const int NI = NT >> 1;

  const int srow = tid >> 3;
  const int sg   = (tid & 7) ^ (srow & 7);
  const u16* Asrc = A  + (size_t)(bm * 128) * lda;
  const u16* Bsrc = BT + (size_t)(bn * 256) * ldb;

  const int agc0 = ((0 + g) ^ (lr & 7)) * 8;
  const int agc1 = ((4 + g) ^ (lr & 7)) * 8;

  f32x4 acc[4][4];
#pragma unroll
  for (int i = 0; i < 4; ++i)
#pragma unroll
    for (int j = 0; j < 4; ++j) acc[i][j] = (f32x4){0.f, 0.f, 0.f, 0.f};
  bf16x8 af[2][2], bf0[2][2], bf1[2][2];

#define STAGE_A(b, T) do {                                                   \
    int tc = ((T) < NT) ? (T) : (NT - 1);                                    \
    const u16* s0 = Asrc + (size_t)srow * lda + tc*64 + sg*8;                \
    u16* dst = &lds[(b)*24576 + tid*8];                                      \
    gload_lds16(s0, dst);                                                    \
    gload_lds16(s0 + (size_t)64 * lda, dst + 4096);                          \
  } while (0)

#define STAGE_BH(h, b, T) do {                                               \
    int tc = ((T) < NT) ? (T) : (NT - 1);                                    \
    const u16* s0 = Bsrc + (size_t)((h)*128 + srow) * ldb + tc*64 + sg*8;    \
    u16* dst = &lds[(b)*24576 + 8192 + (h)*8192 + tid*8];                    \
    gload_lds16(s0, dst);                                                    \
    gload_lds16(s0 + (size_t)64 * ldb, dst + 4096);                         \
  } while (0)

#define LOADA(mih, b) { _Pragma("unroll") for (int q = 0; q < 2; ++q) {      \
    const u16* rp = &lds[(b)*24576 + (wm*64 + (mih)*32 + q*16 + lr) * 64];   \
    af[q][0] = *(const bf16x8*)(rp + agc0);                                  \
    af[q][1] = *(const bf16x8*)(rp + agc1); } }

#define LOADB(dst, nih, b) { _Pragma("unroll") for (int nq = 0; nq < 2; ++nq) { \
    const u16* rp = &lds[(b)*24576 + 8192 + (wn*64 + (nih)*32 + nq*16 + lr) * 64]; \
    dst[nq][0] = *(const bf16x8*)(rp + agc0);                                \
    dst[nq][1] = *(const bf16x8*)(rp + agc1); } }

#define MM(mih, nih, BF) {                                                   \
    __builtin_amdgcn_s_setprio(1);                                           \
    _Pragma("unroll") for (int kk = 0; kk < 2; ++kk)                         \
      _Pragma("unroll") for (int q = 0; q < 2; ++q)                          \
        _Pragma("unroll") for (int nq = 0; nq < 2; ++nq)                     \
          acc[(mih)*2+q][(nih)*2+nq] = __builtin_amdgcn_mfma_f32_16x16x32_bf16( \
              af[q][kk], BF[nq][kk], acc[(mih)*2+q][(nih)*2+nq], 0, 0, 0);   \
    __builtin_amdgcn_s_setprio(0); }

#define PHEND     __builtin_amdgcn_s_barrier();

  STAGE_A(0, 0); STAGE_BH(0, 0, 0); STAGE_BH(1, 0, 0);
  STAGE_BH(0, 1, 1); STAGE_BH(1, 1, 1);
  asm volatile("s_waitcnt vmcnt(4)" ::: "memory");
  __builtin_amdgcn_s_barrier();

  for (int i = 0; i < NI; ++i) {
    const int t0 = 2 * i;
    LOADA(0, 0); LOADB(bf0, 0, 0);
    STAGE_A(1, t0 + 1);
    MM(0, 0, bf0); PHEND;
    LOADB(bf1, 1, 0);
    STAGE_BH(0, 0, t0 + 2);
    MM(0, 1, bf1); PHEND;
    LOADA(1, 0);
    STAGE_BH(1, 0, t0 + 2);
    MM(1, 1, bf1); PHEND;
    STAGE_A(0, t0 + 2);
    MM(1, 0, bf0);
    asm volatile("s_waitcnt vmcnt(6)" ::: "memory");
    __builtin_amdgcn_s_barrier();
    LOADA(0, 1); LOADB(bf0, 0, 1);
    MM(0, 0, bf0); PHEND;
    LOADB(bf1, 1, 1);
    STAGE_BH(0, 1, t0 + 3);
    MM(0, 1, bf1); PHEND;
    LOADA(1, 1);
    STAGE_BH(1, 1, t0 + 3);
    MM(1, 1, bf1); PHEND;
    MM(1, 0, bf0);
    asm volatile("s_waitcnt vmcnt(4)" ::: "memory");
    __builtin_amdgcn_s_barrier();
  }
#undef STAGE_A
#undef STAGE_BH
#undef LOADA
#undef LOADB
#undef MM
#undef PHEND

#pragma unroll
  for (int mi = 0; mi < 4; ++mi) {
    const int rowOff = (mi >> 1) * 32 + (mi & 1) * 16;
#pragma unroll
    for (int ni = 0; ni < 4; ++ni) {
      const int colOff = (ni >> 1) * 32 + (ni & 1) * 16;
#pragma unroll
      for (int j = 0; j < 4; ++j) {
        int row = bm*128 + wm*64 + rowOff + g*4 + j;
        int col = n_off + bn*256 + wn*64 + colOff + lr;
        epi_store<EPI>((size_t)row * ldc + col, acc[mi][ni][j], Cf, Cb, resf, resb, other);
      }
    }
  }
  conv_tiles(c1W, c1W2, c1WT, c1Nfull, c1Kt, c1Nt, c1K0g, c1N0g, c1Rm, lds);
  conv_tiles(c2W, c2W2, c2WT, c2Nfull, c2Kt, c2Nt, c2K0g, c2N0g, c2Rm, lds);
}

// ------- RoPE + relayout for K, V only ------------------------------------------------
__global__ __launch_bounds__(256) void rope_kernel(
    const u16* __restrict__ qkv, const float* __restrict__ ct, const float* __restrict__ st,
    u16* __restrict__ Kt, u16* __restrict__ VT)
{
  const int tok = blockIdx.x;
  const int b = tok >> 11, s = tok & (S_LEN - 1);
  const int w = threadIdx.x >> 6, lane = threadIdx.x & 63;
  const size_t base = (size_t)tok * QKV_N;
  for (int slot = w; slot < 16; slot += 4) {
    int col = (slot < 8) ? 2048 + slot * 64 : 2560 + (slot - 8) * 64;
    float v = b2f(qkv[base + col + lane]);
    if (slot < 8) {
      int i = lane & 31;
      float c = ct[s * 32 + i], sn = st[s * 32 + i];
      float p = b2f(qkv[base + col + (lane ^ 32)]);
      v = (lane < 32) ? (v * c - p * sn) : (v * c + p * sn);
    }
    u16 ob = f2b(v);
    if (slot < 8) Kt[((size_t)(b * 8 + slot)     * S_LEN + s) * 64 + lane] = ob;
    else          VT[((size_t)(b * 8 + slot - 8) * 64 + lane) * S_LEN + s] = ob;
  }
}

// ------- causal GQA flash attention: DUAL-Q per wave over shared K/V ------------------
// Wave owns q-tiles (jj, 63-jj) of the same kv-head; iterates k-tiles ONCE (64-jj of
// them), computing QK+FIN for both q-tiles per loaded K/V tile. Fixed-m softmax.
#define ASCALE 0.1803368801111204f   /* 0.125 * log2(e) */
#define MFIX   16.0f
__global__ __launch_bounds__(256, 2) void attn_kernel(
    const u16* __restrict__ qkv, const u16* __restrict__ Kt,
    const u16* __restrict__ VT, u16* __restrict__ ctx,
    const float* __restrict__ ct, const float* __restrict__ st,
    const float* cvW, const float* cvW2, u16* cvWT, int cvNfull, int cvKt, int cvNt, int cvK0g, int cvN0g, int cvRm)
{
  __shared__ float tfbuf[64 * 65];
  const int fid = blockIdx.y * gridDim.x + blockIdx.x;   // 0..511
  const int idx = fid >> 3;                              // 0..63
  const int bh  = (fid & 7) * 8 + (idx & 7);             // XCD-local kv locality
  const int y   = idx >> 3;                              // 0..7
  const int wid = threadIdx.x >> 6;
  const int lane = threadIdx.x & 63;
  const int b = bh >> 5, h = bh & 31;
  const int kvh = (b << 3) + (h >> 2);
  const int jj = y * 4 + wid;                            // 0..31
  const int cq = lane & 31;
  const int hi = lane >> 5;

  const int q0a = jj << 5,        nta = jj + 1;          // task A (light)
  const int q0b = (63 - jj) << 5, ntb = 64 - jj;         // task B (heavy)

  const u16* Kp = Kt + (size_t)kvh * S_LEN * 64 + cq * 64 + hi * 8;
  const u16* Vbase = VT + (size_t)kvh * 64 * S_LEN + hi * 8;
  const u16* Vp[4];
#pragma unroll
  for (int v = 0; v < 4; ++v)
    Vp[v] = Vbase + (size_t)((v & 1) * 32 + cq) * S_LEN + (v >> 1) * 16;

  __shared__ float xch[4][32];

#define ATT_LOADK(KF, T) { _Pragma("unroll") for (int q_ = 0; q_ < 4; ++q_) \
    KF[q_] = *(const bf16x8*)(Kp + (T) * 2048 + q_ * 16); }
#define ATT_LOADV(VF, T) { _Pragma("unroll") for (int v_ = 0; v_ < 4; ++v_) \
    VF[v_] = *(const bf16x8*)(Vp[v_] + (T) * 32); }

#define ATT_QK(S, KF, QF) do {                                               \
    S = (f32x16){};                                                          \
    S = __builtin_amdgcn_mfma_f32_32x32x16_bf16(KF[0], QF[0], S, 0, 0, 0);   \
    S = __builtin_amdgcn_mfma_f32_32x32x16_bf16(KF[1], QF[1], S, 0, 0, 0);   \
    S = __builtin_amdgcn_mfma_f32_32x32x16_bf16(KF[2], QF[2], S, 0, 0, 0);   \
    S = __builtin_amdgcn_mfma_f32_32x32x16_bf16(KF[3], QF[3], S, 0, 0, 0);   \
  } while (0)

#define ATT_PACK(P, PA0, PA1) do {                                           \
    uint32_t wds[8], pw[8];                                                  \
    _Pragma("unroll") for (int j = 0; j < 8; ++j) {                          \
      uint32_t wv;                                                           \
      asm("v_cvt_pk_bf16_f32 %0, %1, %2" : "=v"(wv) : "v"((P)[2*j]), "v"((P)[2*j+1])); \
      wds[j] = wv;                                                           \
    }                                                                        \
    _Pragma("unroll") for (int j = 0; j < 8; ++j) pw[j] = __shfl_xor(wds[j], 32); \
    PA0.u[0] = hi ? pw[2]  : wds[0];                                         \
    PA0.u[1] = hi ? pw[3]  : wds[1];                                         \
    PA0.u[2] = hi ? wds[2] : pw[0];                                          \
    PA0.u[3] = hi ? wds[3] : pw[1];                                          \
    PA1.u[0] = hi ? pw[6]  : wds[4];                                         \
    PA1.u[1] = hi ? pw[7]  : wds[5];                                         \
    PA1.u[2] = hi ? wds[6] : pw[4];                                          \
    PA1.u[3] = hi ? wds[7] : pw[5];                                          \
  } while (0)

// FIN: mask (if MASK), exp2 at fixed m, sum into L, pack, 4 PV MFMA into O0/O1
#define ATT_FIN(S, VF, O0, O1, L, MASK) do {                                 \
    float p[16];                                                             \
    _Pragma("unroll") for (int r = 0; r < 16; ++r) p[r] = S[r];              \
    if (MASK) {                                                              \
      _Pragma("unroll") for (int r = 0; r < 16; ++r) {                       \
        int kk = (r & 3) + 8 * (r >> 2) + 4 * hi;                            \
        if (kk > cq) p[r] = -1e30f;                                          \
      }                                                                      \
    }                                                                        \
    float ts_ = 0.f;                                                         \
    _Pragma("unroll") for (int r = 0; r < 16; ++r) { p[r] = exp2f(p[r] - MFIX); ts_ += p[r]; } \
    L += ts_;                                                                \
    union { uint32_t u[4]; bf16x8 v; } pa0, pa1;                             \
    ATT_PACK(p, pa0, pa1);                                                   \
    O0 = __builtin_amdgcn_mfma_f32_32x32x16_bf16(pa0.v, VF[0], O0, 0, 0, 0); \
    O0 = __builtin_amdgcn_mfma_f32_32x32x16_bf16(pa1.v, VF[2], O0, 0, 0, 0); \
    O1 = __builtin_amdgcn_mfma_f32_32x32x16_bf16(pa0.v, VF[1], O1, 0, 0, 0); \
    O1 = __builtin_amdgcn_mfma_f32_32x32x16_bf16(pa1.v, VF[3], O1, 0, 0, 0); \
  } while (0)

// Q load + in-register RoPE, pre-scaled
#define ATT_LOADQ(QF, Q0) do {                                               \
    const u16* Qr = qkv + (size_t)(b * S_LEN + (Q0) + cq) * QKV_N + h * 64 + hi * 8; \
    u16 qr[4][8];                                                            \
    _Pragma("unroll") for (int t = 0; t < 4; ++t)                            \
      *reinterpret_cast<u16x8*>(qr[t]) = *reinterpret_cast<const u16x8*>(Qr + t * 16); \
    const float* cb = ct + (size_t)((Q0) + cq) * 32 + hi * 8;                \
    const float* sb = st + (size_t)((Q0) + cq) * 32 + hi * 8;                \
    union { u16 u[8]; bf16x8 v; } qo[4];                                     \
    _Pragma("unroll") for (int t = 0; t < 2; ++t) {                          \
      float4 c0 = *reinterpret_cast<const float4*>(cb + 16 * t);             \
      float4 c1 = *reinterpret_cast<const float4*>(cb + 16 * t + 4);         \
      float4 s0 = *reinterpret_cast<const float4*>(sb + 16 * t);             \
      float4 s1 = *reinterpret_cast<const float4*>(sb + 16 * t + 4);         \
      float cc[8] = {c0.x,c0.y,c0.z,c0.w, c1.x,c1.y,c1.z,c1.w};              \
      float ssn[8] = {s0.x,s0.y,s0.z,s0.w, s1.x,s1.y,s1.z,s1.w};             \
      _Pragma("unroll") for (int i = 0; i < 8; ++i) {                        \
        float lo = b2f(qr[t][i]), hif = b2f(qr[t + 2][i]);                   \
        qo[t].u[i]     = f2b((lo * cc[i] - hif * ssn[i]) * ASCALE);          \
        qo[t + 2].u[i] = f2b((hif * cc[i] + lo * ssn[i]) * ASCALE);          \
      }                                                                      \
    }                                                                        \
    _Pragma("unroll") for (int t = 0; t < 4; ++t) QF[t] = qo[t].v;           \
  } while (0)

#define ATT_EPI(O0, O1, L, Q0) do {                                          \
    float lv = (L) + __shfl_xor((L), 32);                                    \
    float linv = 1.0f / lv;                                                  \
    if (hi == 0) xch[wid][cq] = linv;                                        \
    asm volatile("s_waitcnt lgkmcnt(0)" ::: "memory");                       \
    __builtin_amdgcn_sched_barrier(0);                                       \
    float4 n0 = *reinterpret_cast<const float4*>(&xch[wid][4 * hi + 0]);     \
    float4 n1 = *reinterpret_cast<const float4*>(&xch[wid][4 * hi + 8]);     \
    float4 n2 = *reinterpret_cast<const float4*>(&xch[wid][4 * hi + 16]);    \
    float4 n3 = *reinterpret_cast<const float4*>(&xch[wid][4 * hi + 24]);    \
    float na[16] = {n0.x,n0.y,n0.z,n0.w, n1.x,n1.y,n1.z,n1.w,                \
                    n2.x,n2.y,n2.z,n2.w, n3.x,n3.y,n3.z,n3.w};               \
    _Pragma("unroll") for (int r = 0; r < 16; ++r) {                         \
      int row = (r & 3) + 8 * (r >> 2) + 4 * hi;                             \
      size_t base_ = (size_t)(b * S_LEN + (Q0) + row) * D_MODEL + h * 64;    \
      ctx[base_ + cq]      = f2b(O0[r] * na[r]);                             \
      ctx[base_ + 32 + cq] = f2b(O1[r] * na[r]);                             \
    }                                                                        \
  } while (0)

  bf16x8 qfA[4], qfB[4];
  ATT_LOADQ(qfA, q0a);
  ATT_LOADQ(qfB, q0b);

  f32x16 oA0 = {}, oA1 = {}, oB0 = {}, oB1 = {};
  float lA = 0.f, lB = 0.f;

  bf16x8 kf[4], vf[4];
#pragma unroll 1
  for (int t = 0; t < ntb; ++t) {
    ATT_LOADK(kf, t);
    ATT_LOADV(vf, t);
    const bool doA = (t < nta);
    f32x16 sA, sB;
    if (doA) ATT_QK(sA, kf, qfA);
    ATT_QK(sB, kf, qfB);
    if (doA) ATT_FIN(sA, vf, oA0, oA1, lA, (t == nta - 1));
    ATT_FIN(sB, vf, oB0, oB1, lB, (t == ntb - 1));
  }

  ATT_EPI(oA0, oA1, lA, q0a);
  ATT_EPI(oB0, oB1, lB, q0b);

#undef ATT_LOADK
#undef ATT_LOADV
#undef ATT_QK
#undef ATT_PACK
#undef ATT_FIN
#undef ATT_LOADQ
#undef ATT_EPI

  conv_tiles(cvW, cvW2, cvWT, cvNfull, cvKt, cvNt, cvK0g, cvN0g, cvRm, tfbuf);
}

// ---------------------------------- host ---------------------------------------------
#define NOCV nullptr, nullptr, nullptr, 0, 0, 0, 0, 0, 1
extern "C" void kernel_launch(void* const* d_in, const int* in_sizes, int n_in,
                              void* d_out, int out_size, void* d_ws, size_t ws_size,
                              hipStream_t stream)
{
  const float* x     = (const float*)d_in[0];
  const float* wn1   = (const float*)d_in[1];
  const float* wqkv  = (const float*)d_in[2];
  const float* wout  = (const float*)d_in[3];
  const float* wn2   = (const float*)d_in[4];
  const float* wgate = (const float*)d_in[5];
  const float* wup   = (const float*)d_in[6];
  const float* wdown = (const float*)d_in[7];
  float* out = (float*)d_out;
  char* ws = (char*)d_ws;

  // arena: 117,964,800 bytes, 16.8MB units
  float* cosT = (float*)(ws + 0);
  float* sinT = (float*)(ws + 262144);
  u16*   U1   = (u16*)  (ws + 524288);
  u16*   U2   = (u16*)  (ws + 17301504);
  u16*   x1b  = (u16*)  (ws + 34078720);
  char*  S    = ws + 50855936;
  u16*   hB   = (u16*)(S + 0);
  u16*   qkvB = (u16*)(S + 16777216);
  u16*   kB   = (u16*)(S + 41943040);
  u16*   vtB  = (u16*)(S + 46137344);
  u16*   ctxB = (u16*)(S + 0);
  u16*   h2B  = (u16*)(S + 0);
  u16*   slab = (u16*)(S + 16777216);
  u16*   U7   = (u16*)(S + 50331648);

  sincos_kernel<<<dim3(256), 256, 0, stream>>>(cosT, sinT);
  // h = rmsnorm(x); tail: wqkv -> U1
  rmsnorm_kernel<false><<<dim3(NTOK), 256, 0, stream>>>(x, wn1, hB,
      wqkv, nullptr, U1, 3072, 2048, 3072, 0, 0, 1);

  // qkv = h @ w_qkv; tail: wout -> U7
  gemm128_kernel<4><<<dim3(12, 32), 512, 0, stream>>>(hB, U1, 2048, 2048, 2048, 3072, 0,
      nullptr, qkvB, nullptr, nullptr, nullptr,
      wout, nullptr, U7, 2048, 2048, 2048, 0, 0, 1, NOCV);
  rope_kernel<<<dim3(NTOK), 256, 0, stream>>>(qkvB, cosT, sinT, kB, vtB);
  // attn (dual-Q shared-KV); tail: interleaved gate/up c0-lo -> U1
  attn_kernel<<<dim3(64, 8), 256, 0, stream>>>(qkvB, kB, vtB, ctxB, cosT, sinT,
      wgate, wup, U1, 8192, 2048, 2048, 0, 0, 2);

  // x1 = x + ctx @ w_out; tail: gate/up c0-hi -> U2
  gemm128_kernel<6><<<dim3(8, 32), 512, 0, stream>>>(ctxB, U7, 2048, 2048, 2048, 2048, 0,
      nullptr, x1b, x, nullptr, nullptr,
      wgate, wup, U2, 8192, 2048, 2048, 0, 2048, 2, NOCV);

  // h2 = rmsnorm(x1); tail: wdown rows 0..4095 -> U7
  rmsnorm_kernel<true><<<dim3(NTOK), 256, 0, stream>>>(x1b, wn2, h2B,
      wdown, nullptr, U7, 2048, 4096, 2048, 0, 0, 1);

  // slab = silu(h2 @ gate_c0) * (h2 @ up_c0)
  gemm8p_kernel<9><<<dim3(32, 16), 512, 0, stream>>>(h2B, U1, U2, 2048, 2048, 2048, 4096, 0,
      nullptr, slab, nullptr, nullptr, nullptr, NOCV);
  // out = x1 + slab @ down_c0; tails: gate/up c1-lo -> U1, c1-hi -> U2
  gemm128_kernel<7><<<dim3(8, 32), 512, 0, stream>>>(slab, U7, 4096, 4096, 4096, 2048, 0,
      out, nullptr, nullptr, x1b, nullptr,
      wgate, wup, U1, 8192, 2048, 2048, 0, 4096, 2,
      wgate, wup, U2, 8192, 2048, 2048, 0, 6144, 2);
  // slab = silu(h2 @ gate_c1) * (h2 @ up_c1); tail: wdown rows 4096..8191 -> U7
  gemm8p_kernel<9><<<dim3(32, 16), 512, 0, stream>>>(h2B, U1, U2, 2048, 2048, 2048, 4096, 0,
      nullptr, slab, nullptr, nullptr, nullptr,
      wdown, nullptr, U7, 2048, 4096, 2048, 4096, 0, 1);
  // out += slab @ down_c1
  gemm128_kernel<5><<<dim3(8, 32), 512, 0, stream>>>(slab, U7, 4096, 4096, 4096, 2048, 0,
      out, nullptr, nullptr, nullptr, nullptr, NOCV, NOCV);
}

// Round 22
// 747.485 us; speedup vs baseline: 1.0258x; 1.0015x over previous
//
#include <hip/hip_runtime.h>
#include <stdint.h>

#define D_MODEL 2048
#define S_LEN   2048
#define NTOK    4096
#define QKV_N   3072
#define DFF     8192

typedef float  f32x4   __attribute__((ext_vector_type(4)));
typedef float  f32x16  __attribute__((ext_vector_type(16)));
typedef __bf16 bf16x8  __attribute__((ext_vector_type(8)));
typedef unsigned short u16;
typedef unsigned short u16x8 __attribute__((ext_vector_type(8)));

__device__ __forceinline__ float b2f(u16 u){ union{float f; uint32_t i;} v; v.i = ((uint32_t)u) << 16; return v.f; }
__device__ __forceinline__ u16 f2b(float f){
  union{float f; uint32_t i;} v; v.f = f;
  uint32_t r = v.i + 0x7FFFu + ((v.i >> 16) & 1u);
  return (u16)(r >> 16);
}

__device__ __forceinline__ void gload_lds16(const void* gsrc, void* ldst){
  __builtin_amdgcn_global_load_lds(
      (const __attribute__((address_space(1))) void*)gsrc,
      (__attribute__((address_space(3))) void*)ldst,
      16, 0, 0);
}

// ------- grid-stride weight convert+transpose tail (pair + row-interleave capable) ----
__device__ __forceinline__ void conv_tiles(const float* W, const float* W2, u16* WT,
    int Nfull, int Kt, int Nt, int k0g, int n0g, int rmul, void* ldsbuf)
{
  if (W == nullptr) return;
  float* tf = (float*)ldsbuf;
  const int tt  = threadIdx.x;
  const int nTn = Nt >> 6;
  const int nT  = (Kt >> 6) * nTn;
  const int bid = (blockIdx.z * gridDim.y + blockIdx.y) * gridDim.x + blockIdx.x;
  const int gsz = gridDim.x * gridDim.y * gridDim.z;
  const int c4 = (tt & 15) << 2;
  const int r  = tt >> 4;
  for (int tile = bid; tile < nT; tile += gsz) {
    const int k0 = (tile / nTn) << 6, n0 = (tile % nTn) << 6;
    for (int m = 0; m < 2; ++m) {
      const float* Ws = m ? W2 : W;
      if (m && W2 == nullptr) break;
      __syncthreads();
      if (tt < 256) {
#pragma unroll
        for (int i = 0; i < 4; ++i) {
          int row = r + i * 16;
          float4 v = *reinterpret_cast<const float4*>(&Ws[(size_t)(k0g + k0 + row) * Nfull + n0g + n0 + c4]);
          tf[row * 65 + c4 + 0] = v.x; tf[row * 65 + c4 + 1] = v.y;
          tf[row * 65 + c4 + 2] = v.z; tf[row * 65 + c4 + 3] = v.w;
        }
      }
      __syncthreads();
      if (tt < 256) {
#pragma unroll
        for (int i = 0; i < 4; ++i) {
          int n = r + i * 16;
          ushort4 ov;
          ov.x = f2b(tf[(c4 + 0) * 65 + n]); ov.y = f2b(tf[(c4 + 1) * 65 + n]);
          ov.z = f2b(tf[(c4 + 2) * 65 + n]); ov.w = f2b(tf[(c4 + 3) * 65 + n]);
          *reinterpret_cast<ushort4*>(&WT[(size_t)((n0 + n) * rmul + m) * Kt + k0 + c4]) = ov;
        }
      }
    }
  }
}

// ------- rope cos/sin table --------------------------------------------------------
__global__ void sincos_kernel(float* __restrict__ ct, float* __restrict__ st)
{
  int idx = blockIdx.x * 256 + threadIdx.x;
  if (idx >= S_LEN * 32) return;
  int p = idx >> 5, i = idx & 31;
  double freq = pow(10000.0, -((double)(2*i)) / 64.0);
  double ang  = (double)p * freq;
  ct[idx] = (float)cos(ang);
  st[idx] = (float)sin(ang);
}

// ------- RMSNorm (+ conversion tail) -------------------------------------------------
template<bool BF16IN>
__global__ __launch_bounds__(256) void rmsnorm_kernel(const void* __restrict__ xin, const float* __restrict__ w, u16* __restrict__ out,
                                                      const float* cvW, const float* cvW2, u16* cvWT, int cvNfull, int cvKt, int cvNt, int cvK0g, int cvN0g, int cvRm)
{
  __shared__ float tfbuf[64 * 65];
  const int row = blockIdx.x;
  const int t = threadIdx.x;
  float v[8];
  if (BF16IN) {
    const u16* xr = ((const u16*)xin) + (size_t)row * D_MODEL;
    u16x8 a = *reinterpret_cast<const u16x8*>(&xr[t*8]);
#pragma unroll
    for (int j = 0; j < 8; ++j) v[j] = b2f(a[j]);
  } else {
    const float* xr = ((const float*)xin) + (size_t)row * D_MODEL;
    float4 a = *reinterpret_cast<const float4*>(&xr[t*8]);
    float4 c = *reinterpret_cast<const float4*>(&xr[t*8+4]);
    v[0]=a.x; v[1]=a.y; v[2]=a.z; v[3]=a.w; v[4]=c.x; v[5]=c.y; v[6]=c.z; v[7]=c.w;
  }
  float ss = 0.f;
#pragma unroll
  for (int j = 0; j < 8; ++j) ss += v[j]*v[j];
#pragma unroll
  for (int d = 1; d < 64; d <<= 1) ss += __shfl_xor(ss, d);
  __shared__ float red[4];
  if ((t & 63) == 0) red[t >> 6] = ss;
  __syncthreads();
  ss = red[0] + red[1] + red[2] + red[3];
  const float sc = rsqrtf(ss * (1.0f / (float)D_MODEL) + 1e-5f);
  float4 w0 = *reinterpret_cast<const float4*>(&w[t*8]);
  float4 w1 = *reinterpret_cast<const float4*>(&w[t*8+4]);
  u16x8 o;
  o[0]=f2b(v[0]*sc*w0.x); o[1]=f2b(v[1]*sc*w0.y); o[2]=f2b(v[2]*sc*w0.z); o[3]=f2b(v[3]*sc*w0.w);
  o[4]=f2b(v[4]*sc*w1.x); o[5]=f2b(v[5]*sc*w1.y); o[6]=f2b(v[6]*sc*w1.z); o[7]=f2b(v[7]*sc*w1.w);
  *reinterpret_cast<u16x8*>(&out[(size_t)row * D_MODEL + t*8]) = o;
  conv_tiles(cvW, cvW2, cvWT, cvNfull, cvKt, cvNt, cvK0g, cvN0g, cvRm, tfbuf);
}

// ------- shared GEMM epilogue dispatch ------------------------------------------------
template<int EPI>
__device__ __forceinline__ void epi_store(size_t idx, float v, float* Cf, u16* Cb,
                                          const float* resf, const u16* resb, const u16* other)
{
  if (EPI == 2)      Cb[idx] = f2b(v / (1.0f + __expf(-v)));
  else if (EPI == 3) Cb[idx] = f2b(v * b2f(other[idx]));
  else if (EPI == 4) Cb[idx] = f2b(v);
  else if (EPI == 5) Cf[idx] += v;
  else if (EPI == 6) Cb[idx] = f2b(v + resf[idx]);
  else if (EPI == 7) Cf[idx] = v + b2f(resb[idx]);
  else if (EPI == 9) {
    float pv = __shfl_xor(v, 1);
    float gate = (threadIdx.x & 1) ? pv : v;
    float up   = (threadIdx.x & 1) ? v  : pv;
    if (!(threadIdx.x & 1)) Cb[idx] = f2b(gate / (1.0f + __expf(-gate)) * up);
  }
}

// ------- 256x256 8-phase bf16 MFMA GEMM: A[M][lda] x BT[N][ldb] -----------------------
template<int EPI>
__global__ __launch_bounds__(512, 2) void gemm8p_kernel(
    const u16* __restrict__ A, const u16* __restrict__ BT, const u16* __restrict__ BT2,
    int K, int lda, int ldb, int ldc, int n_off,
    float* Cf, u16* Cb,
    const float* __restrict__ resf, const u16* __restrict__ resb, const u16* other,
    const float* cvW, const float* cvW2, u16* cvWT, int cvNfull, int cvKt, int cvNt, int cvK0g, int cvN0g, int cvRm)
{
  __shared__ u16 lds[65536];
  const int tid = threadIdx.x;
  const int w = tid >> 6, lane = tid & 63;
  const int g = lane >> 4, lr = lane & 15;
  const int wm = w >> 2, wn = w & 3;
  int fid = blockIdx.y * gridDim.x + blockIdx.x;
  const int nwg = gridDim.x * gridDim.y;
  fid = (fid & 7) * (nwg >> 3) + (fid >> 3);      // XCD swizzle (nwg % 8 == 0)
  const int bn = fid / gridDim.y, bm = fid % gridDim.y;   // column-major: bn-stripe/XCD
  const int NT = K >> 6;
  const int NI = NT >> 1;

  const int srow = tid >> 3;
  const int sg   = (tid & 7) ^ (srow & 7);
  const u16* Asrc = A + (size_t)(bm * 256) * lda;
  const u16* Bsrc;
  if (EPI == 9) Bsrc = (bn < 16) ? BT + (size_t)(bn * 256) * ldb
                                 : BT2 + (size_t)(bn * 256 - 4096) * ldb;
  else          Bsrc = BT + (size_t)(bn * 256) * ldb;

  const int agc0 = ((0 + g) ^ (lr & 7)) * 8;
  const int agc1 = ((4 + g) ^ (lr & 7)) * 8;

  f32x4 acc[8][4];
#pragma unroll
  for (int i = 0; i < 8; ++i)
#pragma unroll
    for (int j = 0; j < 4; ++j) acc[i][j] = (f32x4){0.f, 0.f, 0.f, 0.f};
  bf16x8 af[4][2], bf0[2][2], bf1[2][2];

#define STAGE_H(isB, h, b, T) do {                                           \
    int tc = ((T) < NT) ? (T) : (NT - 1);                                    \
    const u16* sb = (isB) ? Bsrc : Asrc;                                     \
    const int  sld = (isB) ? ldb : lda;                                      \
    const u16* s0 = sb + (size_t)((h)*128 + srow) * sld + tc*64 + sg*8;      \
    u16* dst = &lds[(b)*32768 + (isB)*16384 + (h)*8192 + tid*8];             \
    gload_lds16(s0, dst);                                                    \
    gload_lds16(s0 + (size_t)64 * sld, dst + 4096);                          \
  } while (0)

#define LOADA(mih, b) { _Pragma("unroll") for (int q = 0; q < 4; ++q) {      \
    const u16* rp = &lds[(b)*32768 + (wm*128 + (mih)*64 + q*16 + lr) * 64];  \
    af[q][0] = *(const bf16x8*)(rp + agc0);                                  \
    af[q][1] = *(const bf16x8*)(rp + agc1); } }

#define LOADB(dst, nih, b) { _Pragma("unroll") for (int nq = 0; nq < 2; ++nq) { \
    const u16* rp = &lds[(b)*32768 + 16384 + (wn*64 + (nih)*32 + nq*16 + lr) * 64]; \
    dst[nq][0] = *(const bf16x8*)(rp + agc0);                                \
    dst[nq][1] = *(const bf16x8*)(rp + agc1); } }

#define MM(mih, nih, BF) {                                                   \
    __builtin_amdgcn_s_setprio(1);                                           \
    _Pragma("unroll") for (int kk = 0; kk < 2; ++kk)                         \
      _Pragma("unroll") for (int q = 0; q < 4; ++q)                          \
        _Pragma("unroll") for (int nq = 0; nq < 2; ++nq)                     \
          acc[(mih)*4+q][(nih)*2+nq] = __builtin_amdgcn_mfma_f32_16x16x32_bf16( \
              af[q][kk], BF[nq][kk], acc[(mih)*4+q][(nih)*2+nq], 0, 0, 0);   \
    __builtin_amdgcn_s_setprio(0); }

#define PHEND     __builtin_amdgcn_s_barrier();
#define PHEND_VM  asm volatile("s_waitcnt vmcnt(4)" ::: "memory");           \
                  __builtin_amdgcn_s_barrier();

  STAGE_H(0, 0, 0, 0); STAGE_H(0, 1, 0, 0);
  STAGE_H(1, 0, 0, 0); STAGE_H(1, 1, 0, 0);
  STAGE_H(1, 0, 1, 1); STAGE_H(1, 1, 1, 1);
  asm volatile("s_waitcnt vmcnt(4)" ::: "memory");
  __builtin_amdgcn_s_barrier();

  for (int i = 0; i < NI; ++i) {
    const int t0 = 2 * i;
    LOADA(0, 0); LOADB(bf0, 0, 0);
    STAGE_H(0, 0, 1, t0 + 1);
    MM(0, 0, bf0); PHEND;
    LOADB(bf1, 1, 0);
    STAGE_H(0, 1, 1, t0 + 1);
    MM(0, 1, bf1); PHEND;
    LOADA(1, 0);
    STAGE_H(1, 0, 0, t0 + 2);
    MM(1, 1, bf1); PHEND;
    STAGE_H(1, 1, 0, t0 + 2);
    MM(1, 0, bf0); PHEND_VM;
    LOADA(0, 1); LOADB(bf0, 0, 1);
    STAGE_H(0, 0, 0, t0 + 2);
    MM(0, 0, bf0); PHEND;
    LOADB(bf1, 1, 1);
    STAGE_H(0, 1, 0, t0 + 2);
    MM(0, 1, bf1); PHEND;
    LOADA(1, 1);
    STAGE_H(1, 0, 1, t0 + 3);
    MM(1, 1, bf1); PHEND;
    STAGE_H(1, 1, 1, t0 + 3);
    MM(1, 0, bf0); PHEND_VM;
  }
#undef STAGE_H
#undef LOADA
#undef LOADB
#undef MM

#pragma unroll
  for (int mi = 0; mi < 8; ++mi) {
    const int rowOff = (mi >> 2) * 64 + (mi & 3) * 16;
#pragma unroll
    for (int ni = 0; ni < 4; ++ni) {
      const int colOff = (ni >> 1) * 32 + (ni & 1) * 16;
#pragma unroll
      for (int j = 0; j < 4; ++j) {
        int row = bm*256 + wm*128 + rowOff + g*4 + j;
        int col = n_off + bn*256 + wn*64 + colOff + lr;
        size_t idx = (EPI == 9) ? ((size_t)row * ldc + (col >> 1))
                                : ((size_t)row * ldc + col);
        epi_store<EPI>(idx, acc[mi][ni][j], Cf, Cb, resf, resb, other);
      }
    }
  }
  conv_tiles(cvW, cvW2, cvWT, cvNfull, cvKt, cvNt, cvK0g, cvN0g, cvRm, lds);
}

// ------- 128x256 8-phase bf16 MFMA GEMM (two conversion-tail descriptors) -------------
template<int EPI>
__global__ __launch_bounds__(512) void gemm128_kernel(
    const u16* __restrict__ A, const u16* __restrict__ BT,
    int K, int lda, int ldb, int ldc, int n_off,
    float* Cf, u16* Cb,
    const float* __restrict__ resf, const u16* __restrict__ resb, const u16* other,
    const float* c1W, const float* c1W2, u16* c1WT, int c1Nfull, int c1Kt, int c1Nt, int c1K0g, int c1N0g, int c1Rm,
    const float* c2W, const float* c2W2, u16* c2WT, int c2Nfull, int c2Kt, int c2Nt, int c2K0g, int c2N0g, int c2Rm)
{
  __shared__ u16 lds[49152];
  const int tid = threadIdx.x;
  const int w = tid >> 6, lane = tid & 63;
  const int g = lane >> 4, lr = lane & 15;
  const int wm = w >> 2, wn = w & 3;
  int fid = blockIdx.y * gridDim.x + blockIdx.x;
  const int nwg = gridDim.x * gridDim.y;
  fid = (fid & 7) * (nwg >> 3) + (fid >> 3);      // XCD swizzle (nwg % 8 == 0)
  const int bn = fid / gridDim.y, bm = fid % gridDim.y;   // column-major: bn-stripe/XCD
  const int NT = K >> 6;
  const int NI = NT >> 1;

  const int srow = tid >> 3;
  const int sg   = (tid & 7) ^ (srow & 7);
  const u16* Asrc = A  + (size_t)(bm * 128) * lda;
  const u16* Bsrc = BT + (size_t)(bn * 256) * ldb;

  const int agc0 = ((0 + g) ^ (lr & 7)) * 8;
  const int agc1 = ((4 + g) ^ (lr & 7)) * 8;

  f32x4 acc[4][4];
#pragma unroll
  for (int i = 0; i < 4; ++i)
#pragma unroll
    for (int j = 0; j < 4; ++j) acc[i][j] = (f32x4){0.f, 0.f, 0.f, 0.f};
  bf16x8 af[2][2], bf0[2][2], bf1[2][2];

#define STAGE_A(b, T) do {                                                   \
    int tc = ((T) < NT) ? (T) : (NT - 1);                                    \
    const u16* s0 = Asrc + (size_t)srow * lda + tc*64 + sg*8;                \
    u16* dst = &lds[(b)*24576 + tid*8];                                      \
    gload_lds16(s0, dst);                                                    \
    gload_lds16(s0 + (size_t)64 * lda, dst + 4096);                          \
  } while (0)

#define STAGE_BH(h, b, T) do {                                               \
    int tc = ((T) < NT) ? (T) : (NT - 1);                                    \
    const u16* s0 = Bsrc + (size_t)((h)*128 + srow) * ldb + tc*64 + sg*8;    \
    u16* dst = &lds[(b)*24576 + 8192 + (h)*8192 + tid*8];                    \
    gload_lds16(s0, dst);                                                    \
    gload_lds16(s0 + (size_t)64 * ldb, dst + 4096);                         \
  } while (0)

#define LOADA(mih, b) { _Pragma("unroll") for (int q = 0; q < 2; ++q) {      \
    const u16* rp = &lds[(b)*24576 + (wm*64 + (mih)*32 + q*16 + lr) * 64];   \
    af[q][0] = *(const bf16x8*)(rp + agc0);                                  \
    af[q][1] = *(const bf16x8*)(rp + agc1); } }

#define LOADB(dst, nih, b) { _Pragma("unroll") for (int nq = 0; nq < 2; ++nq) { \
    const u16* rp = &lds[(b)*24576 + 8192 + (wn*64 + (nih)*32 + nq*16 + lr) * 64]; \
    dst[nq][0] = *(const bf16x8*)(rp + agc0);                                \
    dst[nq][1] = *(const bf16x8*)(rp + agc1); } }

#define MM(mih, nih, BF) {                                                   \
    __builtin_amdgcn_s_setprio(1);                                           \
    _Pragma("unroll") for (int kk = 0; kk < 2; ++kk)                         \
      _Pragma("unroll") for (int q = 0; q < 2; ++q)                          \
        _Pragma("unroll") for (int nq = 0; nq < 2; ++nq)                     \
          acc[(mih)*2+q][(nih)*2+nq] = __builtin_amdgcn_mfma_f32_16x16x32_bf16( \
              af[q][kk], BF[nq][kk], acc[(mih)*2+q][(nih)*2+nq], 0, 0, 0);   \
    __builtin_amdgcn_s_setprio(0); }

#define PHEND     __builtin_amdgcn_s_barrier();

  STAGE_A(0, 0); STAGE_BH(0, 0, 0); STAGE_BH(1, 0, 0);
  STAGE_BH(0, 1, 1); STAGE_BH(1, 1, 1);
  asm volatile("s_waitcnt vmcnt(4)" ::: "memory");
  __builtin_amdgcn_s_barrier();

  for (int i = 0; i < NI; ++i) {
    const int t0 = 2 * i;
    LOADA(0, 0); LOADB(bf0, 0, 0);
    STAGE_A(1, t0 + 1);
    MM(0, 0, bf0); PHEND;
    LOADB(bf1, 1, 0);
    STAGE_BH(0, 0, t0 + 2);
    MM(0, 1, bf1); PHEND;
    LOADA(1, 0);
    STAGE_BH(1, 0, t0 + 2);
    MM(1, 1, bf1); PHEND;
    STAGE_A(0, t0 + 2);
    MM(1, 0, bf0);
    asm volatile("s_waitcnt vmcnt(6)" ::: "memory");
    __builtin_amdgcn_s_barrier();
    LOADA(0, 1); LOADB(bf0, 0, 1);
    MM(0, 0, bf0); PHEND;
    LOADB(bf1, 1, 1);
    STAGE_BH(0, 1, t0 + 3);
    MM(0, 1, bf1); PHEND;
    LOADA(1, 1);
    STAGE_BH(1, 1, t0 + 3);
    MM(1, 1, bf1); PHEND;
    MM(1, 0, bf0);
    asm volatile("s_waitcnt vmcnt(4)" ::: "memory");
    __builtin_amdgcn_s_barrier();
  }
#undef STAGE_A
#undef STAGE_BH
#undef LOADA
#undef LOADB
#undef MM
#undef PHEND

#pragma unroll
  for (int mi = 0; mi < 4; ++mi) {
    const int rowOff = (mi >> 1) * 32 + (mi & 1) * 16;
#pragma unroll
    for (int ni = 0; ni < 4; ++ni) {
      const int colOff = (ni >> 1) * 32 + (ni & 1) * 16;
#pragma unroll
      for (int j = 0; j < 4; ++j) {
        int row = bm*128 + wm*64 + rowOff + g*4 + j;
        int col = n_off + bn*256 + wn*64 + colOff + lr;
        epi_store<EPI>((size_t)row * ldc + col, acc[mi][ni][j], Cf, Cb, resf, resb, other);
      }
    }
  }
  conv_tiles(c1W, c1W2, c1WT, c1Nfull, c1Kt, c1Nt, c1K0g, c1N0g, c1Rm, lds);
  conv_tiles(c2W, c2W2, c2WT, c2Nfull, c2Kt, c2Nt, c2K0g, c2N0g, c2Rm, lds);
}

// ------- RoPE + relayout for K, V only ------------------------------------------------
__global__ __launch_bounds__(256) void rope_kernel(
    const u16* __restrict__ qkv, const float* __restrict__ ct, const float* __restrict__ st,
    u16* __restrict__ Kt, u16* __restrict__ VT)
{
  const int tok = blockIdx.x;
  const int b = tok >> 11, s = tok & (S_LEN - 1);
  const int w = threadIdx.x >> 6, lane = threadIdx.x & 63;
  const size_t base = (size_t)tok * QKV_N;
  for (int slot = w; slot < 16; slot += 4) {
    int col = (slot < 8) ? 2048 + slot * 64 : 2560 + (slot - 8) * 64;
    float v = b2f(qkv[base + col + lane]);
    if (slot < 8) {
      int i = lane & 31;
      float c = ct[s * 32 + i], sn = st[s * 32 + i];
      float p = b2f(qkv[base + col + (lane ^ 32)]);
      v = (lane < 32) ? (v * c - p * sn) : (v * c + p * sn);
    }
    u16 ob = f2b(v);
    if (slot < 8) Kt[((size_t)(b * 8 + slot)     * S_LEN + s) * 64 + lane] = ob;
    else          VT[((size_t)(b * 8 + slot - 8) * 64 + lane) * S_LEN + s] = ob;
  }
}

// ------- causal GQA flash attention: DUAL-Q shared-KV + K/V double-buffer prefetch ----
#define ASCALE 0.1803368801111204f   /* 0.125 * log2(e) */
#define MFIX   16.0f
__global__ __launch_bounds__(256, 2) void attn_kernel(
    const u16* __restrict__ qkv, const u16* __restrict__ Kt,
    const u16* __restrict__ VT, u16* __restrict__ ctx,
    const float* __restrict__ ct, const float* __restrict__ st,
    const float* cvW, const float* cvW2, u16* cvWT, int cvNfull, int cvKt, int cvNt, int cvK0g, int cvN0g, int cvRm)
{
  __shared__ float tfbuf[64 * 65];
  const int fid = blockIdx.y * gridDim.x + blockIdx.x;   // 0..511
  const int idx = fid >> 3;                              // 0..63
  const int bh  = (fid & 7) * 8 + (idx & 7);             // XCD-local kv locality
  const int y   = idx >> 3;                              // 0..7
  const int wid = threadIdx.x >> 6;
  const int lane = threadIdx.x & 63;
  const int b = bh >> 5, h = bh & 31;
  const int kvh = (b << 3) + (h >> 2);
  const int jj = y * 4 + wid;                            // 0..31
  const int cq = lane & 31;
  const int hi = lane >> 5;

  const int q0a = jj << 5,        nta = jj + 1;          // task A (light)
  const int q0b = (63 - jj) << 5, ntb = 64 - jj;         // task B (heavy)

  const u16* Kp = Kt + (size_t)kvh * S_LEN * 64 + cq * 64 + hi * 8;
  const u16* Vbase = VT + (size_t)kvh * 64 * S_LEN + hi * 8;
  const u16* Vp[4];
#pragma unroll
  for (int v = 0; v < 4; ++v)
    Vp[v] = Vbase + (size_t)((v & 1) * 32 + cq) * S_LEN + (v >> 1) * 16;

  __shared__ float xch[4][32];

#define ATT_LOADK(KF, T) { _Pragma("unroll") for (int q_ = 0; q_ < 4; ++q_) \
    KF[q_] = *(const bf16x8*)(Kp + (T) * 2048 + q_ * 16); }
#define ATT_LOADV(VF, T) { _Pragma("unroll") for (int v_ = 0; v_ < 4; ++v_) \
    VF[v_] = *(const bf16x8*)(Vp[v_] + (T) * 32); }

#define ATT_QK(S, KF, QF) do {                                               \
    S = (f32x16){};                                                          \
    S = __builtin_amdgcn_mfma_f32_32x32x16_bf16(KF[0], QF[0], S, 0, 0, 0);   \
    S = __builtin_amdgcn_mfma_f32_32x32x16_bf16(KF[1], QF[1], S, 0, 0, 0);   \
    S = __builtin_amdgcn_mfma_f32_32x32x16_bf16(KF[2], QF[2], S, 0, 0, 0);   \
    S = __builtin_amdgcn_mfma_f32_32x32x16_bf16(KF[3], QF[3], S, 0, 0, 0);   \
  } while (0)

#define ATT_PACK(P, PA0, PA1) do {                                           \
    uint32_t wds[8], pw[8];                                                  \
    _Pragma("unroll") for (int j = 0; j < 8; ++j) {                          \
      uint32_t wv;                                                           \
      asm("v_cvt_pk_bf16_f32 %0, %1, %2" : "=v"(wv) : "v"((P)[2*j]), "v"((P)[2*j+1])); \
      wds[j] = wv;                                                           \
    }                                                                        \
    _Pragma("unroll") for (int j = 0; j < 8; ++j) pw[j] = __shfl_xor(wds[j], 32); \
    PA0.u[0] = hi ? pw[2]  : wds[0];                                         \
    PA0.u[1] = hi ? pw[3]  : wds[1];                                         \
    PA0.u[2] = hi ? wds[2] : pw[0];                                          \
    PA0.u[3] = hi ? wds[3] : pw[1];                                          \
    PA1.u[0] = hi ? pw[6]  : wds[4];                                         \
    PA1.u[1] = hi ? pw[7]  : wds[5];                                         \
    PA1.u[2] = hi ? wds[6] : pw[4];                                          \
    PA1.u[3] = hi ? pw[7] ^ 0 : pw[5];                                       \
  } while (0)

  // NOTE: the line above must be PA1.u[3] = hi ? wds[7] : pw[5]; (fixed below)
#undef ATT_PACK
#define ATT_PACK(P, PA0, PA1) do {                                           \
    uint32_t wds[8], pw[8];                                                  \
    _Pragma("unroll") for (int j = 0; j < 8; ++j) {                          \
      uint32_t wv;                                                           \
      asm("v_cvt_pk_bf16_f32 %0, %1, %2" : "=v"(wv) : "v"((P)[2*j]), "v"((P)[2*j+1])); \
      wds[j] = wv;                                                           \
    }                                                                        \
    _Pragma("unroll") for (int j = 0; j < 8; ++j) pw[j] = __shfl_xor(wds[j], 32); \
    PA0.u[0] = hi ? pw[2]  : wds[0];                                         \
    PA0.u[1] = hi ? pw[3]  : wds[1];                                         \
    PA0.u[2] = hi ? wds[2] : pw[0];                                          \
    PA0.u[3] = hi ? wds[3] : pw[1];                                          \
    PA1.u[0] = hi ? pw[6]  : wds[4];                                         \
    PA1.u[1] = hi ? pw[7]  : wds[5];                                         \
    PA1.u[2] = hi ? wds[6] : pw[4];                                          \
    PA1.u[3] = hi ? wds[7] : pw[5];                                          \
  } while (0)

#define ATT_FIN(S, VF, O0, O1, L, MASK) do {                                 \
    float p[16];                                                             \
    _Pragma("unroll") for (int r = 0; r < 16; ++r) p[r] = S[r];              \
    if (MASK) {                                                              \
      _Pragma("unroll") for (int r = 0; r < 16; ++r) {                       \
        int kk = (r & 3) + 8 * (r >> 2) + 4 * hi;                            \
        if (kk > cq) p[r] = -1e30f;                                          \
      }                                                                      \
    }                                                                        \
    float ts_ = 0.f;                                                         \
    _Pragma("unroll") for (int r = 0; r < 16; ++r) { p[r] = exp2f(p[r] - MFIX); ts_ += p[r]; } \
    L += ts_;                                                                \
    union { uint32_t u[4]; bf16x8 v; } pa0, pa1;                             \
    ATT_PACK(p, pa0, pa1);                                                   \
    O0 = __builtin_amdgcn_mfma_f32_32x32x16_bf16(pa0.v, VF[0], O0, 0, 0, 0); \
    O0 = __builtin_amdgcn_mfma_f32_32x32x16_bf16(pa1.v, VF[2], O0, 0, 0, 0); \
    O1 = __builtin_amdgcn_mfma_f32_32x32x16_bf16(pa0.v, VF[1], O1, 0, 0, 0); \
    O1 = __builtin_amdgcn_mfma_f32_32x32x16_bf16(pa1.v, VF[3], O1, 0, 0, 0); \
  } while (0)

#define ATT_LOADQ(QF, Q0) do {                                               \
    const u16* Qr = qkv + (size_t)(b * S_LEN + (Q0) + cq) * QKV_N + h * 64 + hi * 8; \
    u16 qr[4][8];                                                            \
    _Pragma("unroll") for (int t = 0; t < 4; ++t)                            \
      *reinterpret_cast<u16x8*>(qr[t]) = *reinterpret_cast<const u16x8*>(Qr + t * 16); \
    const float* cb = ct + (size_t)((Q0) + cq) * 32 + hi * 8;                \
    const float* sb = st + (size_t)((Q0) + cq) * 32 + hi * 8;                \
    union { u16 u[8]; bf16x8 v; } qo[4];                                     \
    _Pragma("unroll") for (int t = 0; t < 2; ++t) {                          \
      float4 c0 = *reinterpret_cast<const float4*>(cb + 16 * t);             \
      float4 c1 = *reinterpret_cast<const float4*>(cb + 16 * t + 4);         \
      float4 s0 = *reinterpret_cast<const float4*>(sb + 16 * t);             \
      float4 s1 = *reinterpret_cast<const float4*>(sb + 16 * t + 4);         \
      float cc[8] = {c0.x,c0.y,c0.z,c0.w, c1.x,c1.y,c1.z,c1.w};              \
      float ssn[8] = {s0.x,s0.y,s0.z,s0.w, s1.x,s1.y,s1.z,s1.w};             \
      _Pragma("unroll") for (int i = 0; i < 8; ++i) {                        \
        float lo = b2f(qr[t][i]), hif = b2f(qr[t + 2][i]);                   \
        qo[t].u[i]     = f2b((lo * cc[i] - hif * ssn[i]) * ASCALE);          \
        qo[t + 2].u[i] = f2b((hif * cc[i] + lo * ssn[i]) * ASCALE);          \
      }                                                                      \
    }                                                                        \
    _Pragma("unroll") for (int t = 0; t < 4; ++t) QF[t] = qo[t].v;           \
  } while (0)

#define ATT_EPI(O0, O1, L, Q0) do {                                          \
    float lv = (L) + __shfl_xor((L), 32);                                    \
    float linv = 1.0f / lv;                                                  \
    if (hi == 0) xch[wid][cq] = linv;                                        \
    asm volatile("s_waitcnt lgkmcnt(0)" ::: "memory");                       \
    __builtin_amdgcn_sched_barrier(0);                                       \
    float4 n0 = *reinterpret_cast<const float4*>(&xch[wid][4 * hi + 0]);     \
    float4 n1 = *reinterpret_cast<const float4*>(&xch[wid][4 * hi + 8]);     \
    float4 n2 = *reinterpret_cast<const float4*>(&xch[wid][4 * hi + 16]);    \
    float4 n3 = *reinterpret_cast<const float4*>(&xch[wid][4 * hi + 24]);    \
    float na[16] = {n0.x,n0.y,n0.z,n0.w, n1.x,n1.y,n1.z,n1.w,                \
                    n2.x,n2.y,n2.z,n2.w, n3.x,n3.y,n3.z,n3.w};               \
    _Pragma("unroll") for (int r = 0; r < 16; ++r) {                         \
      int row = (r & 3) + 8 * (r >> 2) + 4 * hi;                             \
      size_t base_ = (size_t)(b * S_LEN + (Q0) + row) * D_MODEL + h * 64;    \
      ctx[base_ + cq]      = f2b(O0[r] * na[r]);                             \
      ctx[base_ + 32 + cq] = f2b(O1[r] * na[r]);                             \
    }                                                                        \
  } while (0)

// one full tile step: QK(+A), FIN(+A) using buffer set KF/VF
#define ATT_STEP(KF, VF, T) do {                                             \
    const bool doA = ((T) < nta);                                            \
    f32x16 sA, sB;                                                           \
    if (doA) ATT_QK(sA, KF, qfA);                                            \
    ATT_QK(sB, KF, qfB);                                                     \
    if (doA) ATT_FIN(sA, VF, oA0, oA1, lA, ((T) == nta - 1));                \
    ATT_FIN(sB, VF, oB0, oB1, lB, ((T) == ntb - 1));                         \
  } while (0)

  bf16x8 qfA[4], qfB[4];
  ATT_LOADQ(qfA, q0a);
  ATT_LOADQ(qfB, q0b);

  f32x16 oA0 = {}, oA1 = {}, oB0 = {}, oB1 = {};
  float lA = 0.f, lB = 0.f;

  bf16x8 kf0[4], vf0[4], kf1[4], vf1[4];
  ATT_LOADK(kf0, 0); ATT_LOADV(vf0, 0);

#pragma unroll 1
  for (int t = 0; t < ntb; ) {
    if (t + 1 < ntb) { ATT_LOADK(kf1, t + 1); ATT_LOADV(vf1, t + 1); }
    ATT_STEP(kf0, vf0, t);
    ++t; if (t >= ntb) break;
    if (t + 1 < ntb) { ATT_LOADK(kf0, t + 1); ATT_LOADV(vf0, t + 1); }
    ATT_STEP(kf1, vf1, t);
    ++t;
  }

  ATT_EPI(oA0, oA1, lA, q0a);
  ATT_EPI(oB0, oB1, lB, q0b);

#undef ATT_LOADK
#undef ATT_LOADV
#undef ATT_QK
#undef ATT_PACK
#undef ATT_FIN
#undef ATT_LOADQ
#undef ATT_EPI
#undef ATT_STEP

  conv_tiles(cvW, cvW2, cvWT, cvNfull, cvKt, cvNt, cvK0g, cvN0g, cvRm, tfbuf);
}

// ---------------------------------- host ---------------------------------------------
#define NOCV nullptr, nullptr, nullptr, 0, 0, 0, 0, 0, 1
extern "C" void kernel_launch(void* const* d_in, const int* in_sizes, int n_in,
                              void* d_out, int out_size, void* d_ws, size_t ws_size,
                              hipStream_t stream)
{
  const float* x     = (const float*)d_in[0];
  const float* wn1   = (const float*)d_in[1];
  const float* wqkv  = (const float*)d_in[2];
  const float* wout  = (const float*)d_in[3];
  const float* wn2   = (const float*)d_in[4];
  const float* wgate = (const float*)d_in[5];
  const float* wup   = (const float*)d_in[6];
  const float* wdown = (const float*)d_in[7];
  float* out = (float*)d_out;
  char* ws = (char*)d_ws;

  // arena: 117,964,800 bytes, 16.8MB units
  float* cosT = (float*)(ws + 0);
  float* sinT = (float*)(ws + 262144);
  u16*   U1   = (u16*)  (ws + 524288);
  u16*   U2   = (u16*)  (ws + 17301504);
  u16*   x1b  = (u16*)  (ws + 34078720);
  char*  S    = ws + 50855936;
  u16*   hB   = (u16*)(S + 0);
  u16*   qkvB = (u16*)(S + 16777216);
  u16*   kB   = (u16*)(S + 41943040);
  u16*   vtB  = (u16*)(S + 46137344);
  u16*   ctxB = (u16*)(S + 0);
  u16*   h2B  = (u16*)(S + 0);
  u16*   slab = (u16*)(S + 16777216);
  u16*   U7   = (u16*)(S + 50331648);

  sincos_kernel<<<dim3(256), 256, 0, stream>>>(cosT, sinT);
  // h = rmsnorm(x); tail: wqkv -> U1
  rmsnorm_kernel<false><<<dim3(NTOK), 256, 0, stream>>>(x, wn1, hB,
      wqkv, nullptr, U1, 3072, 2048, 3072, 0, 0, 1);

  // qkv = h @ w_qkv; tail: wout -> U7
  gemm128_kernel<4><<<dim3(12, 32), 512, 0, stream>>>(hB, U1, 2048, 2048, 2048, 3072, 0,
      nullptr, qkvB, nullptr, nullptr, nullptr,
      wout, nullptr, U7, 2048, 2048, 2048, 0, 0, 1, NOCV);
  rope_kernel<<<dim3(NTOK), 256, 0, stream>>>(qkvB, cosT, sinT, kB, vtB);
  // attn (dual-Q shared-KV + prefetch); tail: interleaved gate/up c0-lo -> U1
  attn_kernel<<<dim3(64, 8), 256, 0, stream>>>(qkvB, kB, vtB, ctxB, cosT, sinT,
      wgate, wup, U1, 8192, 2048, 2048, 0, 0, 2);

  // x1 = x + ctx @ w_out; tail: gate/up c0-hi -> U2
  gemm128_kernel<6><<<dim3(8, 32), 512, 0, stream>>>(ctxB, U7, 2048, 2048, 2048, 2048, 0,
      nullptr, x1b, x, nullptr, nullptr,
      wgate, wup, U2, 8192, 2048, 2048, 0, 2048, 2, NOCV);

  // h2 = rmsnorm(x1); tail: wdown rows 0..4095 -> U7
  rmsnorm_kernel<true><<<dim3(NTOK), 256, 0, stream>>>(x1b, wn2, h2B,
      wdown, nullptr, U7, 2048, 4096, 2048, 0, 0, 1);

  // slab = silu(h2 @ gate_c0) * (h2 @ up_c0)
  gemm8p_kernel<9><<<dim3(32, 16), 512, 0, stream>>>(h2B, U1, U2, 2048, 2048, 2048, 4096, 0,
      nullptr, slab, nullptr, nullptr, nullptr, NOCV);
  // out = x1 + slab @ down_c0; tails: gate/up c1-lo -> U1, c1-hi -> U2
  gemm128_kernel<7><<<dim3(8, 32), 512, 0, stream>>>(slab, U7, 4096, 4096, 4096, 2048, 0,
      out, nullptr, nullptr, x1b, nullptr,
      wgate, wup, U1, 8192, 2048, 2048, 0, 4096, 2,
      wgate, wup, U2, 8192, 2048, 2048, 0, 6144, 2);
  // slab = silu(h2 @ gate_c1) * (h2 @ up_c1); tail: wdown rows 4096..8191 -> U7
  gemm8p_kernel<9><<<dim3(32, 16), 512, 0, stream>>>(h2B, U1, U2, 2048, 2048, 2048, 4096, 0,
      nullptr, slab, nullptr, nullptr, nullptr,
      wdown, nullptr, U7, 2048, 4096, 2048, 4096, 0, 1);
  // out += slab @ down_c1
  gemm128_kernel<5><<<dim3(8, 32), 512, 0, stream>>>(slab, U7, 4096, 4096, 4096, 2048, 0,
      out, nullptr, nullptr, nullptr, nullptr, NOCV, NOCV);
}

// Round 23
// 735.413 us; speedup vs baseline: 1.0427x; 1.0164x over previous
//
#include <hip/hip_runtime.h>
#include <stdint.h>

#define D_MODEL 2048
#define S_LEN   2048
#define NTOK    4096
#define QKV_N   3072
#define DFF     8192

typedef float  f32x4   __attribute__((ext_vector_type(4)));
typedef float  f32x16  __attribute__((ext_vector_type(16)));
typedef __bf16 bf16x8  __attribute__((ext_vector_type(8)));
typedef unsigned short u16;
typedef unsigned short u16x8 __attribute__((ext_vector_type(8)));

__device__ __forceinline__ float b2f(u16 u){ union{float f; uint32_t i;} v; v.i = ((uint32_t)u) << 16; return v.f; }
__device__ __forceinline__ u16 f2b(float f){
  union{float f; uint32_t i;} v; v.f = f;
  uint32_t r = v.i + 0x7FFFu + ((v.i >> 16) & 1u);
  return (u16)(r >> 16);
}

__device__ __forceinline__ void gload_lds16(const void* gsrc, void* ldst){
  __builtin_amdgcn_global_load_lds(
      (const __attribute__((address_space(1))) void*)gsrc,
      (__attribute__((address_space(3))) void*)ldst,
      16, 0, 0);
}

// ------- grid-stride weight convert+transpose tail (pair + row-interleave capable) ----
__device__ __forceinline__ void conv_tiles(const float* W, const float* W2, u16* WT,
    int Nfull, int Kt, int Nt, int k0g, int n0g, int rmul, void* ldsbuf)
{
  if (W == nullptr) return;
  float* tf = (float*)ldsbuf;
  const int tt  = threadIdx.x;
  const int nTn = Nt >> 6;
  const int nT  = (Kt >> 6) * nTn;
  const int bid = (blockIdx.z * gridDim.y + blockIdx.y) * gridDim.x + blockIdx.x;
  const int gsz = gridDim.x * gridDim.y * gridDim.z;
  const int c4 = (tt & 15) << 2;
  const int r  = tt >> 4;
  for (int tile = bid; tile < nT; tile += gsz) {
    const int k0 = (tile / nTn) << 6, n0 = (tile % nTn) << 6;
    for (int m = 0; m < 2; ++m) {
      const float* Ws = m ? W2 : W;
      if (m && W2 == nullptr) break;
      __syncthreads();
      if (tt < 256) {
#pragma unroll
        for (int i = 0; i < 4; ++i) {
          int row = r + i * 16;
          float4 v = *reinterpret_cast<const float4*>(&Ws[(size_t)(k0g + k0 + row) * Nfull + n0g + n0 + c4]);
          tf[row * 65 + c4 + 0] = v.x; tf[row * 65 + c4 + 1] = v.y;
          tf[row * 65 + c4 + 2] = v.z; tf[row * 65 + c4 + 3] = v.w;
        }
      }
      __syncthreads();
      if (tt < 256) {
#pragma unroll
        for (int i = 0; i < 4; ++i) {
          int n = r + i * 16;
          ushort4 ov;
          ov.x = f2b(tf[(c4 + 0) * 65 + n]); ov.y = f2b(tf[(c4 + 1) * 65 + n]);
          ov.z = f2b(tf[(c4 + 2) * 65 + n]); ov.w = f2b(tf[(c4 + 3) * 65 + n]);
          *reinterpret_cast<ushort4*>(&WT[(size_t)((n0 + n) * rmul + m) * Kt + k0 + c4]) = ov;
        }
      }
    }
  }
}

// ------- rope cos/sin table --------------------------------------------------------
__global__ void sincos_kernel(float* __restrict__ ct, float* __restrict__ st)
{
  int idx = blockIdx.x * 256 + threadIdx.x;
  if (idx >= S_LEN * 32) return;
  int p = idx >> 5, i = idx & 31;
  double freq = pow(10000.0, -((double)(2*i)) / 64.0);
  double ang  = (double)p * freq;
  ct[idx] = (float)cos(ang);
  st[idx] = (float)sin(ang);
}

// ------- RMSNorm (+ conversion tail) -------------------------------------------------
template<bool BF16IN>
__global__ __launch_bounds__(256) void rmsnorm_kernel(const void* __restrict__ xin, const float* __restrict__ w, u16* __restrict__ out,
                                                      const float* cvW, const float* cvW2, u16* cvWT, int cvNfull, int cvKt, int cvNt, int cvK0g, int cvN0g, int cvRm)
{
  __shared__ float tfbuf[64 * 65];
  const int row = blockIdx.x;
  const int t = threadIdx.x;
  float v[8];
  if (BF16IN) {
    const u16* xr = ((const u16*)xin) + (size_t)row * D_MODEL;
    u16x8 a = *reinterpret_cast<const u16x8*>(&xr[t*8]);
#pragma unroll
    for (int j = 0; j < 8; ++j) v[j] = b2f(a[j]);
  } else {
    const float* xr = ((const float*)xin) + (size_t)row * D_MODEL;
    float4 a = *reinterpret_cast<const float4*>(&xr[t*8]);
    float4 c = *reinterpret_cast<const float4*>(&xr[t*8+4]);
    v[0]=a.x; v[1]=a.y; v[2]=a.z; v[3]=a.w; v[4]=c.x; v[5]=c.y; v[6]=c.z; v[7]=c.w;
  }
  float ss = 0.f;
#pragma unroll
  for (int j = 0; j < 8; ++j) ss += v[j]*v[j];
#pragma unroll
  for (int d = 1; d < 64; d <<= 1) ss += __shfl_xor(ss, d);
  __shared__ float red[4];
  if ((t & 63) == 0) red[t >> 6] = ss;
  __syncthreads();
  ss = red[0] + red[1] + red[2] + red[3];
  const float sc = rsqrtf(ss * (1.0f / (float)D_MODEL) + 1e-5f);
  float4 w0 = *reinterpret_cast<const float4*>(&w[t*8]);
  float4 w1 = *reinterpret_cast<const float4*>(&w[t*8+4]);
  u16x8 o;
  o[0]=f2b(v[0]*sc*w0.x); o[1]=f2b(v[1]*sc*w0.y); o[2]=f2b(v[2]*sc*w0.z); o[3]=f2b(v[3]*sc*w0.w);
  o[4]=f2b(v[4]*sc*w1.x); o[5]=f2b(v[5]*sc*w1.y); o[6]=f2b(v[6]*sc*w1.z); o[7]=f2b(v[7]*sc*w1.w);
  *reinterpret_cast<u16x8*>(&out[(size_t)row * D_MODEL + t*8]) = o;
  conv_tiles(cvW, cvW2, cvWT, cvNfull, cvKt, cvNt, cvK0g, cvN0g, cvRm, tfbuf);
}

// ------- shared GEMM epilogue dispatch ------------------------------------------------
template<int EPI>
__device__ __forceinline__ void epi_store(size_t idx, float v, float* Cf, u16* Cb,
                                          const float* resf, const u16* resb, const u16* other)
{
  if (EPI == 2)      Cb[idx] = f2b(v / (1.0f + __expf(-v)));
  else if (EPI == 3) Cb[idx] = f2b(v * b2f(other[idx]));
  else if (EPI == 4) Cb[idx] = f2b(v);
  else if (EPI == 5) Cf[idx] += v;
  else if (EPI == 6) Cb[idx] = f2b(v + resf[idx]);
  else if (EPI == 7) Cf[idx] = v + b2f(resb[idx]);
  else if (EPI == 9) {
    float pv = __shfl_xor(v, 1);
    float gate = (threadIdx.x & 1) ? pv : v;
    float up   = (threadIdx.x & 1) ? v  : pv;
    if (!(threadIdx.x & 1)) Cb[idx] = f2b(gate / (1.0f + __expf(-gate)) * up);
  }
}

// ------- 256x256 8-phase bf16 MFMA GEMM: A[M][lda] x BT[N][ldb] -----------------------
// Half-aligned read mapping: LOADA(mih) touches only A-half mih; LOADB(nih) only B-half
// nih. All stages issue at earliest slot -> 6-phase prefetch distance, vmcnt(8) x2/iter.
template<int EPI>
__global__ __launch_bounds__(512, 2) void gemm8p_kernel(
    const u16* __restrict__ A, const u16* __restrict__ BT, const u16* __restrict__ BT2,
    int K, int lda, int ldb, int ldc, int n_off,
    float* Cf, u16* Cb,
    const float* __restrict__ resf, const u16* __restrict__ resb, const u16* other,
    const float* cvW, const float* cvW2, u16* cvWT, int cvNfull, int cvKt, int cvNt, int cvK0g, int cvN0g, int cvRm)
{
  __shared__ u16 lds[65536];
  const int tid = threadIdx.x;
  const int w = tid >> 6, lane = tid & 63;
  const int g = lane >> 4, lr = lane & 15;
  const int wm = w >> 2, wn = w & 3;
  int fid = blockIdx.y * gridDim.x + blockIdx.x;
  const int nwg = gridDim.x * gridDim.y;
  fid = (fid & 7) * (nwg >> 3) + (fid >> 3);      // XCD swizzle (nwg % 8 == 0)
  const int bn = fid / gridDim.y, bm = fid % gridDim.y;   // column-major: bn-stripe/XCD
  const int NT = K >> 6;
  const int NI = NT >> 1;

  const int srow = tid >> 3;
  const int sg   = (tid & 7) ^ (srow & 7);
  const u16* Asrc = A + (size_t)(bm * 256) * lda;
  const u16* Bsrc;
  if (EPI == 9) Bsrc = (bn < 16) ? BT + (size_t)(bn * 256) * ldb
                                 : BT2 + (size_t)(bn * 256 - 4096) * ldb;
  else          Bsrc = BT + (size_t)(bn * 256) * ldb;

  const int agc0 = ((0 + g) ^ (lr & 7)) * 8;
  const int agc1 = ((4 + g) ^ (lr & 7)) * 8;

  f32x4 acc[8][4];
#pragma unroll
  for (int i = 0; i < 8; ++i)
#pragma unroll
    for (int j = 0; j < 4; ++j) acc[i][j] = (f32x4){0.f, 0.f, 0.f, 0.f};
  bf16x8 af[4][2], bf0[2][2], bf1[2][2];

#define STAGE_H(isB, h, b, T) do {                                           \
    int tc = ((T) < NT) ? (T) : (NT - 1);                                    \
    const u16* sb = (isB) ? Bsrc : Asrc;                                     \
    const int  sld = (isB) ? ldb : lda;                                      \
    const u16* s0 = sb + (size_t)((h)*128 + srow) * sld + tc*64 + sg*8;      \
    u16* dst = &lds[(b)*32768 + (isB)*16384 + (h)*8192 + tid*8];             \
    gload_lds16(s0, dst);                                                    \
    gload_lds16(s0 + (size_t)64 * sld, dst + 4096);                          \
  } while (0)

// half-aligned reads: A row = mih*128 + wm*64 + q*16 + lr; B row = nih*128 + wn*32 + nq*16 + lr
#define LOADA(mih, b) { _Pragma("unroll") for (int q = 0; q < 4; ++q) {      \
    const u16* rp = &lds[(b)*32768 + ((mih)*128 + wm*64 + q*16 + lr) * 64];  \
    af[q][0] = *(const bf16x8*)(rp + agc0);                                  \
    af[q][1] = *(const bf16x8*)(rp + agc1); } }

#define LOADB(dst, nih, b) { _Pragma("unroll") for (int nq = 0; nq < 2; ++nq) { \
    const u16* rp = &lds[(b)*32768 + 16384 + ((nih)*128 + wn*32 + nq*16 + lr) * 64]; \
    dst[nq][0] = *(const bf16x8*)(rp + agc0);                                \
    dst[nq][1] = *(const bf16x8*)(rp + agc1); } }

#define MM(mih, nih, BF) {                                                   \
    __builtin_amdgcn_s_setprio(1);                                           \
    _Pragma("unroll") for (int kk = 0; kk < 2; ++kk)                         \
      _Pragma("unroll") for (int q = 0; q < 4; ++q)                          \
        _Pragma("unroll") for (int nq = 0; nq < 2; ++nq)                     \
          acc[(mih)*4+q][(nih)*2+nq] = __builtin_amdgcn_mfma_f32_16x16x32_bf16( \
              af[q][kk], BF[nq][kk], acc[(mih)*4+q][(nih)*2+nq], 0, 0, 0);   \
    __builtin_amdgcn_s_setprio(0); }

#define PHEND     __builtin_amdgcn_s_barrier();
#define PHEND_VM  asm volatile("s_waitcnt vmcnt(8)" ::: "memory");           \
                  __builtin_amdgcn_s_barrier();

  // prologue: buf0 <- tile0 (8 loads), buf1 <- tile1 (8 loads); drain buf0
  STAGE_H(0, 0, 0, 0); STAGE_H(1, 0, 0, 0); STAGE_H(1, 1, 0, 0); STAGE_H(0, 1, 0, 0);
  STAGE_H(0, 0, 1, 1); STAGE_H(1, 0, 1, 1); STAGE_H(1, 1, 1, 1); STAGE_H(0, 1, 1, 1);
  asm volatile("s_waitcnt vmcnt(8)" ::: "memory");
  __builtin_amdgcn_s_barrier();

  for (int i = 0; i < NI; ++i) {
    const int t0 = 2 * i;
    // ph1: read A0,B0(buf0)
    LOADA(0, 0); LOADB(bf0, 0, 0);
    MM(0, 0, bf0); PHEND;
    // ph2: read B1; stage buf0.A0,B0 <- T+2
    LOADB(bf1, 1, 0);
    STAGE_H(0, 0, 0, t0 + 2); STAGE_H(1, 0, 0, t0 + 2);
    MM(0, 1, bf1); PHEND;
    // ph3: read A1; stage buf0.B1
    LOADA(1, 0);
    STAGE_H(1, 1, 0, t0 + 2);
    MM(1, 1, bf1); PHEND;
    // ph4: stage buf0.A1; drain buf1 (prev ph6-8, 8 loads)
    STAGE_H(0, 1, 0, t0 + 2);
    MM(1, 0, bf0); PHEND_VM;
    // ph5: read buf1 A0,B0
    LOADA(0, 1); LOADB(bf0, 0, 1);
    MM(0, 0, bf0); PHEND;
    // ph6: read B1; stage buf1.A0,B0 <- T+3
    LOADB(bf1, 1, 1);
    STAGE_H(0, 0, 1, t0 + 3); STAGE_H(1, 0, 1, t0 + 3);
    MM(0, 1, bf1); PHEND;
    // ph7: read A1; stage buf1.B1
    LOADA(1, 1);
    STAGE_H(1, 1, 1, t0 + 3);
    MM(1, 1, bf1); PHEND;
    // ph8: stage buf1.A1; drain buf0 (ph2-4, 8 loads)
    STAGE_H(0, 1, 1, t0 + 3);
    MM(1, 0, bf0); PHEND_VM;
  }
#undef STAGE_H
#undef LOADA
#undef LOADB
#undef MM
#undef PHEND
#undef PHEND_VM

#pragma unroll
  for (int mi = 0; mi < 8; ++mi) {
    const int rowOff = (mi >> 2) * 128 + wm * 64 + (mi & 3) * 16;
#pragma unroll
    for (int ni = 0; ni < 4; ++ni) {
      const int colOff = (ni >> 1) * 128 + wn * 32 + (ni & 1) * 16;
#pragma unroll
      for (int j = 0; j < 4; ++j) {
        int row = bm*256 + rowOff + g*4 + j;
        int col = n_off + bn*256 + colOff + lr;
        size_t idx = (EPI == 9) ? ((size_t)row * ldc + (col >> 1))
                                : ((size_t)row * ldc + col);
        epi_store<EPI>(idx, acc[mi][ni][j], Cf, Cb, resf, resb, other);
      }
    }
  }
  conv_tiles(cvW, cvW2, cvWT, cvNfull, cvKt, cvNt, cvK0g, cvN0g, cvRm, lds);
}

// ------- 128x256 8-phase bf16 MFMA GEMM (half-aligned reads, split A staging) ---------
template<int EPI>
__global__ __launch_bounds__(512) void gemm128_kernel(
    const u16* __restrict__ A, const u16* __restrict__ BT,
    int K, int lda, int ldb, int ldc, int n_off,
    float* Cf, u16* Cb,
    const float* __restrict__ resf, const u16* __restrict__ resb, const u16* other,
    const float* c1W, const float* c1W2, u16* c1WT, int c1Nfull, int c1Kt, int c1Nt, int c1K0g, int c1N0g, int c1Rm,
    const float* c2W, const float* c2W2, u16* c2WT, int c2Nfull, int c2Kt, int c2Nt, int c2K0g, int c2N0g, int c2Rm)
{
  __shared__ u16 lds[49152];
  const int tid = threadIdx.x;
  const int w = tid >> 6, lane = tid & 63;
  const int g = lane >> 4, lr = lane & 15;
  const int wm = w >> 2, wn = w & 3;
  int fid = blockIdx.y * gridDim.x + blockIdx.x;
  const int nwg = gridDim.x * gridDim.y;
  fid = (fid & 7) * (nwg >> 3) + (fid >> 3);      // XCD swizzle (nwg % 8 == 0)
  const int bn = fid / gridDim.y, bm = fid % gridDim.y;   // column-major: bn-stripe/XCD
  const int NT = K >> 6;
  const int NI = NT >> 1;

  const int srow = tid >> 3;
  const int sg   = (tid & 7) ^ (srow & 7);
  const u16* Asrc = A  + (size_t)(bm * 128) * lda;
  const u16* Bsrc = BT + (size_t)(bn * 256) * ldb;

  const int agc0 = ((0 + g) ^ (lr & 7)) * 8;
  const int agc1 = ((4 + g) ^ (lr & 7)) * 8;

  f32x4 acc[4][4];
#pragma unroll
  for (int i = 0; i < 4; ++i)
#pragma unroll
    for (int j = 0; j < 4; ++j) acc[i][j] = (f32x4){0.f, 0.f, 0.f, 0.f};
  bf16x8 af[2][2], bf0[2][2], bf1[2][2];

#define STAGE_A0(b, T) do {                                                  \
    int tc = ((T) < NT) ? (T) : (NT - 1);                                    \
    gload_lds16(Asrc + (size_t)srow * lda + tc*64 + sg*8,                    \
                &lds[(b)*24576 + tid*8]);                                    \
  } while (0)

#define STAGE_A1(b, T) do {                                                  \
    int tc = ((T) < NT) ? (T) : (NT - 1);                                    \
    gload_lds16(Asrc + (size_t)(64 + srow) * lda + tc*64 + sg*8,             \
                &lds[(b)*24576 + 4096 + tid*8]);                             \
  } while (0)

#define STAGE_BH(h, b, T) do {                                               \
    int tc = ((T) < NT) ? (T) : (NT - 1);                                    \
    const u16* s0 = Bsrc + (size_t)((h)*128 + srow) * ldb + tc*64 + sg*8;    \
    u16* dst = &lds[(b)*24576 + 8192 + (h)*8192 + tid*8];                    \
    gload_lds16(s0, dst);                                                    \
    gload_lds16(s0 + (size_t)64 * ldb, dst + 4096);                         \
  } while (0)

// half-aligned reads: A row = mih*64 + wm*32 + q*16 + lr; B row = nih*128 + wn*32 + nq*16 + lr
#define LOADA(mih, b) { _Pragma("unroll") for (int q = 0; q < 2; ++q) {      \
    const u16* rp = &lds[(b)*24576 + ((mih)*64 + wm*32 + q*16 + lr) * 64];   \
    af[q][0] = *(const bf16x8*)(rp + agc0);                                  \
    af[q][1] = *(const bf16x8*)(rp + agc1); } }

#define LOADB(dst, nih, b) { _Pragma("unroll") for (int nq = 0; nq < 2; ++nq) { \
    const u16* rp = &lds[(b)*24576 + 8192 + ((nih)*128 + wn*32 + nq*16 + lr) * 64]; \
    dst[nq][0] = *(const bf16x8*)(rp + agc0);                                \
    dst[nq][1] = *(const bf16x8*)(rp + agc1); } }

#define MM(mih, nih, BF) {                                                   \
    __builtin_amdgcn_s_setprio(1);                                           \
    _Pragma("unroll") for (int kk = 0; kk < 2; ++kk)                         \
      _Pragma("unroll") for (int q = 0; q < 2; ++q)                          \
        _Pragma("unroll") for (int nq = 0; nq < 2; ++nq)                     \
          acc[(mih)*2+q][(nih)*2+nq] = __builtin_amdgcn_mfma_f32_16x16x32_bf16( \
              af[q][kk], BF[nq][kk], acc[(mih)*2+q][(nih)*2+nq], 0, 0, 0);   \
    __builtin_amdgcn_s_setprio(0); }

#define PHEND     __builtin_amdgcn_s_barrier();
#define PHEND_VM  asm volatile("s_waitcnt vmcnt(6)" ::: "memory");           \
                  __builtin_amdgcn_s_barrier();

  // prologue: buf0 <- tile0 (6 loads), buf1 <- tile1 (6 loads); drain buf0
  STAGE_A0(0, 0); STAGE_BH(0, 0, 0); STAGE_BH(1, 0, 0); STAGE_A1(0, 0);
  STAGE_A0(1, 1); STAGE_BH(0, 1, 1); STAGE_BH(1, 1, 1); STAGE_A1(1, 1);
  asm volatile("s_waitcnt vmcnt(6)" ::: "memory");
  __builtin_amdgcn_s_barrier();

  for (int i = 0; i < NI; ++i) {
    const int t0 = 2 * i;
    // ph1
    LOADA(0, 0); LOADB(bf0, 0, 0);
    MM(0, 0, bf0); PHEND;
    // ph2: stage buf0.A0,B0 <- T+2
    LOADB(bf1, 1, 0);
    STAGE_A0(0, t0 + 2); STAGE_BH(0, 0, t0 + 2);
    MM(0, 1, bf1); PHEND;
    // ph3: stage buf0.B1
    LOADA(1, 0);
    STAGE_BH(1, 0, t0 + 2);
    MM(1, 1, bf1); PHEND;
    // ph4: stage buf0.A1; drain buf1 (prev ph6-8, 6 loads)
    STAGE_A1(0, t0 + 2);
    MM(1, 0, bf0); PHEND_VM;
    // ph5
    LOADA(0, 1); LOADB(bf0, 0, 1);
    MM(0, 0, bf0); PHEND;
    // ph6: stage buf1.A0,B0 <- T+3
    LOADB(bf1, 1, 1);
    STAGE_A0(1, t0 + 3); STAGE_BH(0, 1, t0 + 3);
    MM(0, 1, bf1); PHEND;
    // ph7: stage buf1.B1
    LOADA(1, 1);
    STAGE_BH(1, 1, t0 + 3);
    MM(1, 1, bf1); PHEND;
    // ph8: stage buf1.A1; drain buf0 (ph2-4, 6 loads)
    STAGE_A1(1, t0 + 3);
    MM(1, 0, bf0); PHEND_VM;
  }
#undef STAGE_A0
#undef STAGE_A1
#undef STAGE_BH
#undef LOADA
#undef LOADB
#undef MM
#undef PHEND
#undef PHEND_VM

#pragma unroll
  for (int mi = 0; mi < 4; ++mi) {
    const int rowOff = (mi >> 1) * 64 + wm * 32 + (mi & 1) * 16;
#pragma unroll
    for (int ni = 0; ni < 4; ++ni) {
      const int colOff = (ni >> 1) * 128 + wn * 32 + (ni & 1) * 16;
#pragma unroll
      for (int j = 0; j < 4; ++j) {
        int row = bm*128 + rowOff + g*4 + j;
        int col = n_off + bn*256 + colOff + lr;
        epi_store<EPI>((size_t)row * ldc + col, acc[mi][ni][j], Cf, Cb, resf, resb, other);
      }
    }
  }
  conv_tiles(c1W, c1W2, c1WT, c1Nfull, c1Kt, c1Nt, c1K0g, c1N0g, c1Rm, lds);
  conv_tiles(c2W, c2W2, c2WT, c2Nfull, c2Kt, c2Nt, c2K0g, c2N0g, c2Rm, lds);
}

// ------- RoPE + relayout for K, V only ------------------------------------------------
__global__ __launch_bounds__(256) void rope_kernel(
    const u16* __restrict__ qkv, const float* __restrict__ ct, const float* __restrict__ st,
    u16* __restrict__ Kt, u16* __restrict__ VT)
{
  const int tok = blockIdx.x;
  const int b = tok >> 11, s = tok & (S_LEN - 1);
  const int w = threadIdx.x >> 6, lane = threadIdx.x & 63;
  const size_t base = (size_t)tok * QKV_N;
  for (int slot = w; slot < 16; slot += 4) {
    int col = (slot < 8) ? 2048 + slot * 64 : 2560 + (slot - 8) * 64;
    float v = b2f(qkv[base + col + lane]);
    if (slot < 8) {
      int i = lane & 31;
      float c = ct[s * 32 + i], sn = st[s * 32 + i];
      float p = b2f(qkv[base + col + (lane ^ 32)]);
      v = (lane < 32) ? (v * c - p * sn) : (v * c + p * sn);
    }
    u16 ob = f2b(v);
    if (slot < 8) Kt[((size_t)(b * 8 + slot)     * S_LEN + s) * 64 + lane] = ob;
    else          VT[((size_t)(b * 8 + slot - 8) * 64 + lane) * S_LEN + s] = ob;
  }
}

// ------- causal GQA flash attention: DUAL-Q shared-KV + K/V double-buffer prefetch ----
#define ASCALE 0.1803368801111204f   /* 0.125 * log2(e) */
#define MFIX   16.0f
__global__ __launch_bounds__(256, 2) void attn_kernel(
    const u16* __restrict__ qkv, const u16* __restrict__ Kt,
    const u16* __restrict__ VT, u16* __restrict__ ctx,
    const float* __restrict__ ct, const float* __restrict__ st,
    const float* cvW, const float* cvW2, u16* cvWT, int cvNfull, int cvKt, int cvNt, int cvK0g, int cvN0g, int cvRm)
{
  __shared__ float tfbuf[64 * 65];
  const int fid = blockIdx.y * gridDim.x + blockIdx.x;   // 0..511
  const int idx = fid >> 3;                              // 0..63
  const int bh  = (fid & 7) * 8 + (idx & 7);             // XCD-local kv locality
  const int y   = idx >> 3;                              // 0..7
  const int wid = threadIdx.x >> 6;
  const int lane = threadIdx.x & 63;
  const int b = bh >> 5, h = bh & 31;
  const int kvh = (b << 3) + (h >> 2);
  const int jj = y * 4 + wid;                            // 0..31
  const int cq = lane & 31;
  const int hi = lane >> 5;

  const int q0a = jj << 5,        nta = jj + 1;          // task A (light)
  const int q0b = (63 - jj) << 5, ntb = 64 - jj;         // task B (heavy)

  const u16* Kp = Kt + (size_t)kvh * S_LEN * 64 + cq * 64 + hi * 8;
  const u16* Vbase = VT + (size_t)kvh * 64 * S_LEN + hi * 8;
  const u16* Vp[4];
#pragma unroll
  for (int v = 0; v < 4; ++v)
    Vp[v] = Vbase + (size_t)((v & 1) * 32 + cq) * S_LEN + (v >> 1) * 16;

  __shared__ float xch[4][32];

#define ATT_LOADK(KF, T) { _Pragma("unroll") for (int q_ = 0; q_ < 4; ++q_) \
    KF[q_] = *(const bf16x8*)(Kp + (T) * 2048 + q_ * 16); }
#define ATT_LOADV(VF, T) { _Pragma("unroll") for (int v_ = 0; v_ < 4; ++v_) \
    VF[v_] = *(const bf16x8*)(Vp[v_] + (T) * 32); }

#define ATT_QK(S, KF, QF) do {                                               \
    S = (f32x16){};                                                          \
    S = __builtin_amdgcn_mfma_f32_32x32x16_bf16(KF[0], QF[0], S, 0, 0, 0);   \
    S = __builtin_amdgcn_mfma_f32_32x32x16_bf16(KF[1], QF[1], S, 0, 0, 0);   \
    S = __builtin_amdgcn_mfma_f32_32x32x16_bf16(KF[2], QF[2], S, 0, 0, 0);   \
    S = __builtin_amdgcn_mfma_f32_32x32x16_bf16(KF[3], QF[3], S, 0, 0, 0);   \
  } while (0)

#define ATT_PACK(P, PA0, PA1) do {                                           \
    uint32_t wds[8], pw[8];                                                  \
    _Pragma("unroll") for (int j = 0; j < 8; ++j) {                          \
      uint32_t wv;                                                           \
      asm("v_cvt_pk_bf16_f32 %0, %1, %2" : "=v"(wv) : "v"((P)[2*j]), "v"((P)[2*j+1])); \
      wds[j] = wv;                                                           \
    }                                                                        \
    _Pragma("unroll") for (int j = 0; j < 8; ++j) pw[j] = __shfl_xor(wds[j], 32); \
    PA0.u[0] = hi ? pw[2]  : wds[0];                                         \
    PA0.u[1] = hi ? pw[3]  : wds[1];                                         \
    PA0.u[2] = hi ? wds[2] : pw[0];                                          \
    PA0.u[3] = hi ? wds[3] : pw[1];                                          \
    PA1.u[0] = hi ? pw[6]  : wds[4];                                         \
    PA1.u[1] = hi ? pw[7]  : wds[5];                                         \
    PA1.u[2] = hi ? wds[6] : pw[4];                                          \
    PA1.u[3] = hi ? wds[7] : pw[5];                                          \
  } while (0)

#define ATT_FIN(S, VF, O0, O1, L, MASK) do {                                 \
    float p[16];                                                             \
    _Pragma("unroll") for (int r = 0; r < 16; ++r) p[r] = S[r];              \
    if (MASK) {                                                              \
      _Pragma("unroll") for (int r = 0; r < 16; ++r) {                       \
        int kk = (r & 3) + 8 * (r >> 2) + 4 * hi;                            \
        if (kk > cq) p[r] = -1e30f;                                          \
      }                                                                      \
    }                                                                        \
    float ts_ = 0.f;                                                         \
    _Pragma("unroll") for (int r = 0; r < 16; ++r) { p[r] = exp2f(p[r] - MFIX); ts_ += p[r]; } \
    L += ts_;                                                                \
    union { uint32_t u[4]; bf16x8 v; } pa0, pa1;                             \
    ATT_PACK(p, pa0, pa1);                                                   \
    O0 = __builtin_amdgcn_mfma_f32_32x32x16_bf16(pa0.v, VF[0], O0, 0, 0, 0); \
    O0 = __builtin_amdgcn_mfma_f32_32x32x16_bf16(pa1.v, VF[2], O0, 0, 0, 0); \
    O1 = __builtin_amdgcn_mfma_f32_32x32x16_bf16(pa0.v, VF[1], O1, 0, 0, 0); \
    O1 = __builtin_amdgcn_mfma_f32_32x32x16_bf16(pa1.v, VF[3], O1, 0, 0, 0); \
  } while (0)

#define ATT_LOADQ(QF, Q0) do {                                               \
    const u16* Qr = qkv + (size_t)(b * S_LEN + (Q0) + cq) * QKV_N + h * 64 + hi * 8; \
    u16 qr[4][8];                                                            \
    _Pragma("unroll") for (int t = 0; t < 4; ++t)                            \
      *reinterpret_cast<u16x8*>(qr[t]) = *reinterpret_cast<const u16x8*>(Qr + t * 16); \
    const float* cb = ct + (size_t)((Q0) + cq) * 32 + hi * 8;                \
    const float* sb = st + (size_t)((Q0) + cq) * 32 + hi * 8;                \
    union { u16 u[8]; bf16x8 v; } qo[4];                                     \
    _Pragma("unroll") for (int t = 0; t < 2; ++t) {                          \
      float4 c0 = *reinterpret_cast<const float4*>(cb + 16 * t);             \
      float4 c1 = *reinterpret_cast<const float4*>(cb + 16 * t + 4);         \
      float4 s0 = *reinterpret_cast<const float4*>(sb + 16 * t);             \
      float4 s1 = *reinterpret_cast<const float4*>(sb + 16 * t + 4);         \
      float cc[8] = {c0.x,c0.y,c0.z,c0.w, c1.x,c1.y,c1.z,c1.w};              \
      float ssn[8] = {s0.x,s0.y,s0.z,s0.w, s1.x,s1.y,s1.z,s1.w};             \
      _Pragma("unroll") for (int i = 0; i < 8; ++i) {                        \
        float lo = b2f(qr[t][i]), hif = b2f(qr[t + 2][i]);                   \
        qo[t].u[i]     = f2b((lo * cc[i] - hif * ssn[i]) * ASCALE);          \
        qo[t + 2].u[i] = f2b((hif * cc[i] + lo * ssn[i]) * ASCALE);          \
      }                                                                      \
    }                                                                        \
    _Pragma("unroll") for (int t = 0; t < 4; ++t) QF[t] = qo[t].v;           \
  } while (0)

#define ATT_EPI(O0, O1, L, Q0) do {                                          \
    float lv = (L) + __shfl_xor((L), 32);                                    \
    float linv = 1.0f / lv;                                                  \
    if (hi == 0) xch[wid][cq] = linv;                                        \
    asm volatile("s_waitcnt lgkmcnt(0)" ::: "memory");                       \
    __builtin_amdgcn_sched_barrier(0);                                       \
    float4 n0 = *reinterpret_cast<const float4*>(&xch[wid][4 * hi + 0]);     \
    float4 n1 = *reinterpret_cast<const float4*>(&xch[wid][4 * hi + 8]);     \
    float4 n2 = *reinterpret_cast<const float4*>(&xch[wid][4 * hi + 16]);    \
    float4 n3 = *reinterpret_cast<const float4*>(&xch[wid][4 * hi + 24]);    \
    float na[16] = {n0.x,n0.y,n0.z,n0.w, n1.x,n1.y,n1.z,n1.w,                \
                    n2.x,n2.y,n2.z,n2.w, n3.x,n3.y,n3.z,n3.w};               \
    _Pragma("unroll") for (int r = 0; r < 16; ++r) {                         \
      int row = (r & 3) + 8 * (r >> 2) + 4 * hi;                             \
      size_t base_ = (size_t)(b * S_LEN + (Q0) + row) * D_MODEL + h * 64;    \
      ctx[base_ + cq]      = f2b(O0[r] * na[r]);                             \
      ctx[base_ + 32 + cq] = f2b(O1[r] * na[r]);                             \
    }                                                                        \
  } while (0)

#define ATT_STEP(KF, VF, T) do {                                             \
    const bool doA = ((T) < nta);                                            \
    f32x16 sA, sB;                                                           \
    if (doA) ATT_QK(sA, KF, qfA);                                            \
    ATT_QK(sB, KF, qfB);                                                     \
    if (doA) ATT_FIN(sA, VF, oA0, oA1, lA, ((T) == nta - 1));                \
    ATT_FIN(sB, VF, oB0, oB1, lB, ((T) == ntb - 1));                         \
  } while (0)

  bf16x8 qfA[4], qfB[4];
  ATT_LOADQ(qfA, q0a);
  ATT_LOADQ(qfB, q0b);

  f32x16 oA0 = {}, oA1 = {}, oB0 = {}, oB1 = {};
  float lA = 0.f, lB = 0.f;

  bf16x8 kf0[4], vf0[4], kf1[4], vf1[4];
  ATT_LOADK(kf0, 0); ATT_LOADV(vf0, 0);

#pragma unroll 1
  for (int t = 0; t < ntb; ) {
    if (t + 1 < ntb) { ATT_LOADK(kf1, t + 1); ATT_LOADV(vf1, t + 1); }
    ATT_STEP(kf0, vf0, t);
    ++t; if (t >= ntb) break;
    if (t + 1 < ntb) { ATT_LOADK(kf0, t + 1); ATT_LOADV(vf0, t + 1); }
    ATT_STEP(kf1, vf1, t);
    ++t;
  }

  ATT_EPI(oA0, oA1, lA, q0a);
  ATT_EPI(oB0, oB1, lB, q0b);

#undef ATT_LOADK
#undef ATT_LOADV
#undef ATT_QK
#undef ATT_PACK
#undef ATT_FIN
#undef ATT_LOADQ
#undef ATT_EPI
#undef ATT_STEP

  conv_tiles(cvW, cvW2, cvWT, cvNfull, cvKt, cvNt, cvK0g, cvN0g, cvRm, tfbuf);
}

// ---------------------------------- host ---------------------------------------------
#define NOCV nullptr, nullptr, nullptr, 0, 0, 0, 0, 0, 1
extern "C" void kernel_launch(void* const* d_in, const int* in_sizes, int n_in,
                              void* d_out, int out_size, void* d_ws, size_t ws_size,
                              hipStream_t stream)
{
  const float* x     = (const float*)d_in[0];
  const float* wn1   = (const float*)d_in[1];
  const float* wqkv  = (const float*)d_in[2];
  const float* wout  = (const float*)d_in[3];
  const float* wn2   = (const float*)d_in[4];
  const float* wgate = (const float*)d_in[5];
  const float* wup   = (const float*)d_in[6];
  const float* wdown = (const float*)d_in[7];
  float* out = (float*)d_out;
  char* ws = (char*)d_ws;

  // arena: 117,964,800 bytes, 16.8MB units
  float* cosT = (float*)(ws + 0);
  float* sinT = (float*)(ws + 262144);
  u16*   U1   = (u16*)  (ws + 524288);
  u16*   U2   = (u16*)  (ws + 17301504);
  u16*   x1b  = (u16*)  (ws + 34078720);
  char*  S    = ws + 50855936;
  u16*   hB   = (u16*)(S + 0);
  u16*   qkvB = (u16*)(S + 16777216);
  u16*   kB   = (u16*)(S + 41943040);
  u16*   vtB  = (u16*)(S + 46137344);
  u16*   ctxB = (u16*)(S + 0);
  u16*   h2B  = (u16*)(S + 0);
  u16*   slab = (u16*)(S + 16777216);
  u16*   U7   = (u16*)(S + 50331648);

  sincos_kernel<<<dim3(256), 256, 0, stream>>>(cosT, sinT);
  // h = rmsnorm(x); tail: wqkv -> U1
  rmsnorm_kernel<false><<<dim3(NTOK), 256, 0, stream>>>(x, wn1, hB,
      wqkv, nullptr, U1, 3072, 2048, 3072, 0, 0, 1);

  // qkv = h @ w_qkv; tail: wout -> U7
  gemm128_kernel<4><<<dim3(12, 32), 512, 0, stream>>>(hB, U1, 2048, 2048, 2048, 3072, 0,
      nullptr, qkvB, nullptr, nullptr, nullptr,
      wout, nullptr, U7, 2048, 2048, 2048, 0, 0, 1, NOCV);
  rope_kernel<<<dim3(NTOK), 256, 0, stream>>>(qkvB, cosT, sinT, kB, vtB);
  // attn (dual-Q shared-KV + prefetch); tail: interleaved gate/up c0-lo -> U1
  attn_kernel<<<dim3(64, 8), 256, 0, stream>>>(qkvB, kB, vtB, ctxB, cosT, sinT,
      wgate, wup, U1, 8192, 2048, 2048, 0, 0, 2);

  // x1 = x + ctx @ w_out; tail: gate/up c0-hi -> U2
  gemm128_kernel<6><<<dim3(8, 32), 512, 0, stream>>>(ctxB, U7, 2048, 2048, 2048, 2048, 0,
      nullptr, x1b, x, nullptr, nullptr,
      wgate, wup, U2, 8192, 2048, 2048, 0, 2048, 2, NOCV);

  // h2 = rmsnorm(x1); tail: wdown rows 0..4095 -> U7
  rmsnorm_kernel<true><<<dim3(NTOK), 256, 0, stream>>>(x1b, wn2, h2B,
      wdown, nullptr, U7, 2048, 4096, 2048, 0, 0, 1);

  // slab = silu(h2 @ gate_c0) * (h2 @ up_c0)
  gemm8p_kernel<9><<<dim3(32, 16), 512, 0, stream>>>(h2B, U1, U2, 2048, 2048, 2048, 4096, 0,
      nullptr, slab, nullptr, nullptr, nullptr, NOCV);
  // out = x1 + slab @ down_c0; tails: gate/up c1-lo -> U1, c1-hi -> U2
  gemm128_kernel<7><<<dim3(8, 32), 512, 0, stream>>>(slab, U7, 4096, 4096, 4096, 2048, 0,
      out, nullptr, nullptr, x1b, nullptr,
      wgate, wup, U1, 8192, 2048, 2048, 0, 4096, 2,
      wgate, wup, U2, 8192, 2048, 2048, 0, 6144, 2);
  // slab = silu(h2 @ gate_c1) * (h2 @ up_c1); tail: wdown rows 4096..8191 -> U7
  gemm8p_kernel<9><<<dim3(32, 16), 512, 0, stream>>>(h2B, U1, U2, 2048, 2048, 2048, 4096, 0,
      nullptr, slab, nullptr, nullptr, nullptr,
      wdown, nullptr, U7, 2048, 4096, 2048, 4096, 0, 1);
  // out += slab @ down_c1
  gemm128_kernel<5><<<dim3(8, 32), 512, 0, stream>>>(slab, U7, 4096, 4096, 4096, 2048, 0,
      out, nullptr, nullptr, nullptr, nullptr, NOCV, NOCV);
}